// Round 1
// baseline (308.010 us; speedup 1.0000x reference)
//
#include <hip/hip_runtime.h>

// ---------------------------------------------------------------------------
// ImprovedEdgeGNN forward — MI355X
// Sizes: B=8, N=512, D=512, H=256, E=32, C=2
// out layout: [0:16) logits [8,2], [16] total_loss, [17:17+8*512*512) wadj
// ---------------------------------------------------------------------------

#define Bsz 8
#define Nn  512
#define Dd  512
#define Hh  256
#define Ee  32

// ws offsets (floats)
#define WS_NF    0L           // [8,512,512]
#define WS_E1    2097152L     // [8,512,32]  (be folded in)
#define WS_E2    2228224L     // [8,512,32]
#define WS_WADJ  2359296L     // [8,512,512] aligned copy
#define WS_RS    4456448L     // [8,512]     raw row sums (= imp)
#define WS_L0    4460544L     // [1]
#define WS_HAGG  4460548L     // [8,512,512]
#define WS_H     6557700L     // [8,512,256]
#define WS_GR    7606276L     // [8,256]

// K1: L2 normalize rows + e1 = nf@Wa + be, e2 = nf@Wb. One block per (b,i).
__global__ __launch_bounds__(256) void norm_e12_kernel(
    const float* __restrict__ nfeat, const float* __restrict__ Wa,
    const float* __restrict__ Wb, const float* __restrict__ be,
    float* __restrict__ nf, float* __restrict__ e1, float* __restrict__ e2,
    float* __restrict__ l0_sum)
{
  const int row = blockIdx.x;      // b*N + i
  const int t = threadIdx.x;
  __shared__ float xs[512];
  __shared__ float red[256];

  const float2 v = *(const float2*)(nfeat + (long)row*Dd + t*2);
  red[t] = v.x*v.x + v.y*v.y;
  __syncthreads();
  for (int s = 128; s > 0; s >>= 1) { if (t < s) red[t] += red[t+s]; __syncthreads(); }
  const float scale = 1.f / fmaxf(sqrtf(red[0]), 1e-12f);
  __syncthreads();  // red reused below

  const float nx = v.x*scale, ny = v.y*scale;
  xs[t*2] = nx; xs[t*2+1] = ny;
  *(float2*)(nf + (long)row*Dd + t*2) = make_float2(nx, ny);
  if (row == 0 && t == 0) *l0_sum = 0.f;   // K2 (later in stream) accumulates
  __syncthreads();

  // 64 outputs (32 e1 + 32 e2), 4 partial d-ranges per output
  const int o = t & 63;
  const int part = t >> 6;
  const float* W = (o < 32) ? Wa : Wb;
  const int e = o & 31;
  float acc = 0.f;
  const int d0 = part*128;
  #pragma unroll 4
  for (int d = d0; d < d0+128; ++d) acc += xs[d]*W[d*Ee + e];
  red[t] = acc;
  __syncthreads();
  if (t < 64) {
    float s = red[t] + red[t+64] + red[t+128] + red[t+192];
    if (o < 32) e1[(long)row*Ee + e] = s + be[e];
    else        e2[(long)row*Ee + e] = s;
  }
}

// K2: edge scores -> gate -> wadj (to d_out and aligned ws), row sums, l0 sum.
// One block per (b,i), thread covers j = t, t+256.
__global__ __launch_bounds__(256) void edge_kernel(
    const float* __restrict__ e1, const float* __restrict__ e2,
    const float* __restrict__ W2e, const float* __restrict__ b2e,
    const float* __restrict__ adjs, float* __restrict__ out_wadj,
    float* __restrict__ wadj_ws, float* __restrict__ row_sum,
    float* __restrict__ l0_sum)
{
  const int row = blockIdx.x;      // b*N + i
  const int b = row >> 9;
  const int t = threadIdx.x;
  __shared__ float e1s[32], w2s[32];
  __shared__ float red[256];
  if (t < 32) { e1s[t] = e1[(long)row*Ee + t]; w2s[t] = W2e[t]; }
  __syncthreads();
  const float b2 = b2e[0];

  float rs = 0.f, l0 = 0.f;
  #pragma unroll
  for (int jj = 0; jj < 2; ++jj) {
    const int j = t + jj*256;
    const float4* p = (const float4*)(e2 + ((long)(b*Nn + j))*Ee);
    float s = 0.f;
    #pragma unroll
    for (int k = 0; k < 8; ++k) {
      const float4 vv = p[k];
      s += fmaxf(e1s[4*k+0]+vv.x, 0.f)*w2s[4*k+0];
      s += fmaxf(e1s[4*k+1]+vv.y, 0.f)*w2s[4*k+1];
      s += fmaxf(e1s[4*k+2]+vv.z, 0.f)*w2s[4*k+2];
      s += fmaxf(e1s[4*k+3]+vv.w, 0.f)*w2s[4*k+3];
    }
    const float logA = s + b2;
    const float sg = 1.f/(1.f + expf(-logA));
    const float gate = fminf(fmaxf(sg*1.2f - 0.1f, 0.f), 1.f);  // zeta-gamma=1.2, gamma=-0.1
    const float a = adjs[(long)row*Nn + j];
    const float w = gate*a*a;            // adjs * (gate*adjs)
    out_wadj[(long)row*Nn + j] = w;
    wadj_ws[(long)row*Nn + j] = w;
    rs += w;
    // l0 term: sigmoid(logAlpha - beta*log(-gamma/zeta)) = sigmoid(logA + 1.58261088)
    l0 += 1.f/(1.f + expf(-(logA + 1.58261088f)));
  }
  red[t] = rs; __syncthreads();
  for (int s2 = 128; s2 > 0; s2 >>= 1) { if (t < s2) red[t] += red[t+s2]; __syncthreads(); }
  if (t == 0) row_sum[row] = red[0];
  __syncthreads();
  red[t] = l0; __syncthreads();
  for (int s2 = 128; s2 > 0; s2 >>= 1) { if (t < s2) red[t] += red[t+s2]; __syncthreads(); }
  if (t == 0) atomicAdd(l0_sum, red[0]);
}

// Generic tiled f32 GEMM: C[b] = op(A[b] @ B[b]); 64x64 tile, 4x4 microtile.
// rowsum != null -> scale row m by 1/(rowsum[b*rs_stride+m]+1e-8)
// bias != null   -> add bias[n];  do_relu -> relu
__global__ __launch_bounds__(256) void gemm_tile(
    const float* __restrict__ A, const float* __restrict__ B, float* __restrict__ C,
    int M, int Nd, int K, long sAb, long sBb, long sCb,
    const float* __restrict__ rowsum, int rs_stride,
    const float* __restrict__ bias, int do_relu)
{
  const int bb = blockIdx.z;
  const float* Ab = A + (long)bb*sAb;
  const float* Bb = B + (long)bb*sBb;
  float* Cb = C + (long)bb*sCb;
  const int mt = blockIdx.y*64;
  const int nt = blockIdx.x*64;
  const int tid = threadIdx.x;
  const int tx = tid & 15, ty = tid >> 4;
  __shared__ float As[16][65];
  __shared__ float Bs[16][64];
  float c[4][4] = {};
  const int lm = tid >> 2;          // 0..63
  const int lk = (tid & 3)*4;       // 0,4,8,12
  const int lbn = tid & 63;
  const int lbk = tid >> 6;         // 0..3

  for (int kt = 0; kt < K; kt += 16) {
    const float4 av = *(const float4*)(Ab + (long)(mt+lm)*K + kt + lk);
    As[lk+0][lm] = av.x; As[lk+1][lm] = av.y; As[lk+2][lm] = av.z; As[lk+3][lm] = av.w;
    #pragma unroll
    for (int kk = 0; kk < 4; ++kk) {
      const int k = lbk*4 + kk;
      Bs[k][lbn] = Bb[(long)(kt+k)*Nd + nt + lbn];
    }
    __syncthreads();
    #pragma unroll
    for (int k = 0; k < 16; ++k) {
      const float a0 = As[k][ty*4+0], a1 = As[k][ty*4+1];
      const float a2 = As[k][ty*4+2], a3 = As[k][ty*4+3];
      const float b0 = Bs[k][tx*4+0], b1 = Bs[k][tx*4+1];
      const float b2v = Bs[k][tx*4+2], b3 = Bs[k][tx*4+3];
      c[0][0] += a0*b0; c[0][1] += a0*b1; c[0][2] += a0*b2v; c[0][3] += a0*b3;
      c[1][0] += a1*b0; c[1][1] += a1*b1; c[1][2] += a1*b2v; c[1][3] += a1*b3;
      c[2][0] += a2*b0; c[2][1] += a2*b1; c[2][2] += a2*b2v; c[2][3] += a2*b3;
      c[3][0] += a3*b0; c[3][1] += a3*b1; c[3][2] += a3*b2v; c[3][3] += a3*b3;
    }
    __syncthreads();
  }
  #pragma unroll
  for (int i = 0; i < 4; ++i) {
    const int m = mt + ty*4 + i;
    float scale = 1.f;
    if (rowsum) scale = 1.f/(rowsum[bb*rs_stride + m] + 1e-8f);
    #pragma unroll
    for (int j = 0; j < 4; ++j) {
      const int n = nt + tx*4 + j;
      float v = c[i][j]*scale;
      if (bias) v += bias[n];
      if (do_relu) v = fmaxf(v, 0.f);
      Cb[(long)m*Nd + n] = v;
    }
  }
}

// K5: masked softmax over raw degree (imp), attention-pool h -> graph_rep.
// One block per batch.
__global__ __launch_bounds__(256) void pool_kernel(
    const float* __restrict__ row_sum, const float* __restrict__ masks,
    const float* __restrict__ h, float* __restrict__ graph_rep)
{
  const int b = blockIdx.x;
  const int t = threadIdx.x;
  __shared__ float attn[512];
  __shared__ float red[256];
  const float m0 = masks[b*Nn + t], m1 = masks[b*Nn + t + 256];
  const float l0 = (m0 > 0.f) ? row_sum[b*Nn + t] : -1e9f;
  const float l1 = (m1 > 0.f) ? row_sum[b*Nn + t + 256] : -1e9f;
  red[t] = fmaxf(l0, l1); __syncthreads();
  for (int s = 128; s > 0; s >>= 1) { if (t < s) red[t] = fmaxf(red[t], red[t+s]); __syncthreads(); }
  const float mx = red[0];
  __syncthreads();
  const float e0 = expf(l0 - mx), e1v = expf(l1 - mx);
  attn[t] = e0; attn[t+256] = e1v;
  red[t] = e0 + e1v; __syncthreads();
  for (int s = 128; s > 0; s >>= 1) { if (t < s) red[t] += red[t+s]; __syncthreads(); }
  const float sinv = 1.f/red[0];
  __syncthreads();
  float acc = 0.f;
  for (int i = 0; i < Nn; ++i) acc += attn[i]*h[((long)b*Nn + i)*Hh + t];
  graph_rep[b*Hh + t] = acc*sinv;
}

// K6: classifier head + spectral norm + losses. Single block.
__global__ __launch_bounds__(256) void classifier_kernel(
    const float* __restrict__ gr, const float* __restrict__ W1c,
    const float* __restrict__ b1c, const float* __restrict__ ln_g,
    const float* __restrict__ ln_b, const float* __restrict__ W2c,
    const float* __restrict__ b2c, const float* __restrict__ u_sn,
    const int* __restrict__ labels, const float* __restrict__ l0_sum,
    float* __restrict__ out)
{
  const int t = threadIdx.x;
  __shared__ float grs[2048];
  __shared__ float z[8][128];
  __shared__ float red[256];
  __shared__ float vv[128];
  __shared__ float mu_s[8], ri_s[8];
  __shared__ float lg[16];
  for (int p = t; p < 2048; p += 256) grs[p] = gr[p];
  __syncthreads();
  #pragma unroll
  for (int p = 0; p < 4; ++p) {
    const int idx = t + p*256;
    const int b = idx >> 7, o = idx & 127;
    float acc = b1c[o];
    for (int d = 0; d < 256; ++d) acc += grs[b*256 + d]*W1c[d*128 + o];
    z[b][o] = fmaxf(acc, 0.f);
  }
  __syncthreads();
  if (t < 8) {
    float mu = 0.f;
    for (int o = 0; o < 128; ++o) mu += z[t][o];
    mu *= (1.f/128.f);
    float var = 0.f;
    for (int o = 0; o < 128; ++o) { const float d = z[t][o]-mu; var += d*d; }
    var *= (1.f/128.f);
    mu_s[t] = mu; ri_s[t] = rsqrtf(var + 1e-5f);
  }
  // spectral norm: v = W2c@u, normalize; u2 = W2c^T@v_hat, normalize; sigma = v_hat@(W2c@u2_hat)
  const float u0 = u_sn[0], u1 = u_sn[1];
  float vt = 0.f;
  if (t < 128) { vt = W2c[2*t]*u0 + W2c[2*t+1]*u1; vv[t] = vt; }
  red[t] = (t < 128) ? vt*vt : 0.f;
  __syncthreads();
  for (int s = 128; s > 0; s >>= 1) { if (t < s) red[t] += red[t+s]; __syncthreads(); }
  const float vninv = 1.f/fmaxf(sqrtf(red[0]), 1e-12f);
  __syncthreads();
  red[t] = (t < 128) ? W2c[2*t]*vv[t]*vninv : 0.f;
  __syncthreads();
  for (int s = 128; s > 0; s >>= 1) { if (t < s) red[t] += red[t+s]; __syncthreads(); }
  const float u20 = red[0];
  __syncthreads();
  red[t] = (t < 128) ? W2c[2*t+1]*vv[t]*vninv : 0.f;
  __syncthreads();
  for (int s = 128; s > 0; s >>= 1) { if (t < s) red[t] += red[t+s]; __syncthreads(); }
  const float u21 = red[0];
  __syncthreads();
  const float uninv = 1.f/fmaxf(sqrtf(u20*u20 + u21*u21), 1e-12f);
  const float u2n0 = u20*uninv, u2n1 = u21*uninv;
  red[t] = (t < 128) ? vv[t]*vninv*(W2c[2*t]*u2n0 + W2c[2*t+1]*u2n1) : 0.f;
  __syncthreads();
  for (int s = 128; s > 0; s >>= 1) { if (t < s) red[t] += red[t+s]; __syncthreads(); }
  const float sinv = 1.f/red[0];
  __syncthreads();
  if (t < 16) {
    const int b = t >> 1, c = t & 1;
    const float mu = mu_s[b], ri = ri_s[b];
    float acc = 0.f;
    for (int o = 0; o < 128; ++o) {
      const float zln = (z[b][o]-mu)*ri*ln_g[o] + ln_b[o];
      acc += zln*W2c[2*o + c];
    }
    const float lgv = acc*sinv + b2c[c];
    lg[t] = lgv;
    out[t] = lgv;
  }
  __syncthreads();
  if (t == 0) {
    float closs = 0.f;
    for (int b = 0; b < 8; ++b) {
      const float a0 = lg[2*b], a1 = lg[2*b+1];
      const float m = fmaxf(a0, a1);
      const float lse = m + logf(expf(a0-m) + expf(a1-m));
      closs += lse - lg[2*b + labels[b]];
    }
    closs *= (1.f/8.f);
    out[16] = closs + 0.01f*l0_sum[0];
  }
}

extern "C" void kernel_launch(void* const* d_in, const int* in_sizes, int n_in,
                              void* d_out, int out_size, void* d_ws, size_t ws_size,
                              hipStream_t stream) {
  const float* node_feat = (const float*)d_in[0];
  const int*   labels    = (const int*)d_in[1];
  const float* adjs      = (const float*)d_in[2];
  const float* masks     = (const float*)d_in[3];
  const float* Wa        = (const float*)d_in[4];
  const float* Wb        = (const float*)d_in[5];
  const float* be        = (const float*)d_in[6];
  const float* W2e       = (const float*)d_in[7];
  const float* b2e       = (const float*)d_in[8];
  const float* Wconv     = (const float*)d_in[9];
  const float* bconv     = (const float*)d_in[10];
  const float* W1c       = (const float*)d_in[11];
  const float* b1c       = (const float*)d_in[12];
  const float* ln_g      = (const float*)d_in[13];
  const float* ln_b      = (const float*)d_in[14];
  const float* W2c       = (const float*)d_in[15];
  const float* b2c       = (const float*)d_in[16];
  const float* u_sn      = (const float*)d_in[17];

  float* out = (float*)d_out;
  float* ws  = (float*)d_ws;
  float* nf      = ws + WS_NF;
  float* e1      = ws + WS_E1;
  float* e2      = ws + WS_E2;
  float* wadj    = ws + WS_WADJ;
  float* row_sum = ws + WS_RS;
  float* l0s     = ws + WS_L0;
  float* h_agg   = ws + WS_HAGG;
  float* h       = ws + WS_H;
  float* gr      = ws + WS_GR;

  norm_e12_kernel<<<Bsz*Nn, 256, 0, stream>>>(node_feat, Wa, Wb, be, nf, e1, e2, l0s);
  edge_kernel<<<Bsz*Nn, 256, 0, stream>>>(e1, e2, W2e, b2e, adjs, out + 17, wadj,
                                          row_sum, l0s);
  // h_agg[b] = (wadj[b]/rowsum) @ nf[b]
  gemm_tile<<<dim3(Nn/64, Nn/64, Bsz), 256, 0, stream>>>(
      wadj, nf, h_agg, Nn, Dd, Nn,
      (long)Nn*Nn, (long)Nn*Dd, (long)Nn*Dd, row_sum, Nn, nullptr, 0);
  // h = relu(h_agg @ Wconv + bconv), flat M = 4096
  gemm_tile<<<dim3(Hh/64, (Bsz*Nn)/64, 1), 256, 0, stream>>>(
      h_agg, Wconv, h, Bsz*Nn, Hh, Dd,
      0, 0, 0, nullptr, 0, bconv, 1);
  pool_kernel<<<Bsz, 256, 0, stream>>>(row_sum, masks, h, gr);
  classifier_kernel<<<1, 256, 0, stream>>>(gr, W1c, b1c, ln_g, ln_b, W2c, b2c,
                                           u_sn, labels, l0s, out);
}

// Round 2
// 277.291 us; speedup vs baseline: 1.1108x; 1.1108x over previous
//
#include <hip/hip_runtime.h>

// ---------------------------------------------------------------------------
// ImprovedEdgeGNN forward — MI355X
// Sizes: B=8, N=512, D=512, H=256, E=32, C=2
// out layout: [0:16) logits [8,2], [16] total_loss, [17:17+8*512*512) wadj
// R2: tiled edge kernel (latency-bound 66us -> ~8us), parallel pooling.
// ---------------------------------------------------------------------------

#define Bsz 8
#define Nn  512
#define Dd  512
#define Hh  256
#define Ee  32

// ws offsets (floats)
#define WS_NF    0L           // [8,512,512]
#define WS_E1    2097152L     // [8,512,32]  (be folded in) -- reused as attn after edge
#define WS_E2    2228224L     // [8,512,32]
#define WS_WADJ  2359296L     // [8,512,512] aligned copy
#define WS_RS    4456448L     // [8,512]     raw row sums (= imp)
#define WS_L0    4460544L     // [1]
#define WS_HAGG  4460548L     // [8,512,512]
#define WS_H     6557700L     // [8,512,256]
#define WS_GR    7606276L     // [8,256]

// K1: L2 normalize rows + e1 = nf@Wa + be, e2 = nf@Wb. One block per (b,i).
// Also zeroes row_sum[row] and (row 0) l0_sum for edge_kernel's atomics.
__global__ __launch_bounds__(256) void norm_e12_kernel(
    const float* __restrict__ nfeat, const float* __restrict__ Wa,
    const float* __restrict__ Wb, const float* __restrict__ be,
    float* __restrict__ nf, float* __restrict__ e1, float* __restrict__ e2,
    float* __restrict__ row_sum, float* __restrict__ l0_sum)
{
  const int row = blockIdx.x;      // b*N + i
  const int t = threadIdx.x;
  __shared__ float xs[512];
  __shared__ float red[256];

  const float2 v = *(const float2*)(nfeat + (long)row*Dd + t*2);
  red[t] = v.x*v.x + v.y*v.y;
  __syncthreads();
  for (int s = 128; s > 0; s >>= 1) { if (t < s) red[t] += red[t+s]; __syncthreads(); }
  const float scale = 1.f / fmaxf(sqrtf(red[0]), 1e-12f);
  __syncthreads();  // red reused below

  const float nx = v.x*scale, ny = v.y*scale;
  xs[t*2] = nx; xs[t*2+1] = ny;
  *(float2*)(nf + (long)row*Dd + t*2) = make_float2(nx, ny);
  if (t == 0) {
    row_sum[row] = 0.f;
    if (row == 0) *l0_sum = 0.f;
  }
  __syncthreads();

  // 64 outputs (32 e1 + 32 e2), 4 partial d-ranges per output
  const int o = t & 63;
  const int part = t >> 6;
  const float* W = (o < 32) ? Wa : Wb;
  const int e = o & 31;
  float acc = 0.f;
  const int d0 = part*128;
  #pragma unroll 4
  for (int d = d0; d < d0+128; ++d) acc += xs[d]*W[d*Ee + e];
  red[t] = acc;
  __syncthreads();
  if (t < 64) {
    float s = red[t] + red[t+64] + red[t+128] + red[t+192];
    if (o < 32) e1[(long)row*Ee + e] = s + be[e];
    else        e2[(long)row*Ee + e] = s;
  }
}

// K2: tiled edge scoring. Block = (b, 32-row i-tile, 128-col j-tile).
// e2 tile staged transposed (k-major, stride 132) in LDS; e1 rows + W2e in
// VGPRs. Each thread: 2 i x 8 j, 16 independent accumulators.
__global__ __launch_bounds__(256) void edge_kernel(
    const float* __restrict__ e1, const float* __restrict__ e2,
    const float* __restrict__ W2e, const float* __restrict__ b2e,
    const float* __restrict__ adjs, float* __restrict__ out_wadj,
    float* __restrict__ wadj_ws, float* __restrict__ row_sum,
    float* __restrict__ l0_sum)
{
  const int b  = blockIdx.z;
  const int i0 = blockIdx.y * 32;
  const int j0 = blockIdx.x * 128;
  const int t  = threadIdx.x;

  __shared__ float e2s[32*132];  // [k][j], padded stride 132 (2-way max conflict)

  // stage e2 tile transposed: global [j][k] -> LDS [k][j]; coalesced reads.
  #pragma unroll
  for (int itr = 0; itr < 4; ++itr) {
    const int idx = t + itr*256;          // 0..1023
    const int kq = idx & 7, jg = idx >> 3; // kq: k-quad, jg: local j
    const float4 v = *(const float4*)(e2 + ((long)(b*Nn + j0 + jg))*Ee + kq*4);
    e2s[(kq*4+0)*132 + jg] = v.x;
    e2s[(kq*4+1)*132 + jg] = v.y;
    e2s[(kq*4+2)*132 + jg] = v.z;
    e2s[(kq*4+3)*132 + jg] = v.w;
  }

  const int pair  = t >> 4;            // 0..15 -> i pair
  const int jslot = t & 15;            // 0..15 -> j chunk
  const int ia = i0 + pair*2;
  const int ib = ia + 1;
  const int ja = jslot*4;              // local j of first chunk
  const int jb = ja + 64;              // local j of second chunk

  // e1 rows and W2e into registers (redundant across lanes -> L1 broadcast)
  float e1af[32], e1bf[32], w2f[32];
  #pragma unroll
  for (int q = 0; q < 8; ++q) {
    *(float4*)(&e1af[q*4]) = *(const float4*)(e1 + ((long)(b*Nn + ia))*Ee + q*4);
    *(float4*)(&e1bf[q*4]) = *(const float4*)(e1 + ((long)(b*Nn + ib))*Ee + q*4);
    *(float4*)(&w2f[q*4])  = *(const float4*)(W2e + q*4);
  }
  const float b2 = b2e[0];
  __syncthreads();

  float acc[2][8] = {};
  #pragma unroll
  for (int k = 0; k < 32; ++k) {
    const float4 va = *(const float4*)(e2s + k*132 + ja);
    const float4 vb = *(const float4*)(e2s + k*132 + jb);
    const float w = w2f[k];
    const float ea = e1af[k], eb = e1bf[k];
    acc[0][0] += fmaxf(ea+va.x, 0.f)*w;
    acc[0][1] += fmaxf(ea+va.y, 0.f)*w;
    acc[0][2] += fmaxf(ea+va.z, 0.f)*w;
    acc[0][3] += fmaxf(ea+va.w, 0.f)*w;
    acc[0][4] += fmaxf(ea+vb.x, 0.f)*w;
    acc[0][5] += fmaxf(ea+vb.y, 0.f)*w;
    acc[0][6] += fmaxf(ea+vb.z, 0.f)*w;
    acc[0][7] += fmaxf(ea+vb.w, 0.f)*w;
    acc[1][0] += fmaxf(eb+va.x, 0.f)*w;
    acc[1][1] += fmaxf(eb+va.y, 0.f)*w;
    acc[1][2] += fmaxf(eb+va.z, 0.f)*w;
    acc[1][3] += fmaxf(eb+va.w, 0.f)*w;
    acc[1][4] += fmaxf(eb+vb.x, 0.f)*w;
    acc[1][5] += fmaxf(eb+vb.y, 0.f)*w;
    acc[1][6] += fmaxf(eb+vb.z, 0.f)*w;
    acc[1][7] += fmaxf(eb+vb.w, 0.f)*w;
  }

  float rs[2] = {0.f, 0.f};
  float l0acc = 0.f;
  #pragma unroll
  for (int ii = 0; ii < 2; ++ii) {
    const int i = (ii == 0) ? ia : ib;
    const float* arow = adjs     + ((long)(b*Nn + i))*Nn + j0;
    float* wsrow      = wadj_ws  + ((long)(b*Nn + i))*Nn + j0;
    float* outrow     = out_wadj + ((long)(b*Nn + i))*Nn + j0;
    #pragma unroll
    for (int h2 = 0; h2 < 2; ++h2) {
      const int jl = (h2 == 0) ? ja : jb;
      const float4 av = *(const float4*)(arow + jl);
      float wv[4];
      #pragma unroll
      for (int c = 0; c < 4; ++c) {
        const float logA = acc[ii][h2*4 + c] + b2;
        const float sg = 1.f/(1.f + expf(-logA));
        const float gate = fminf(fmaxf(sg*1.2f - 0.1f, 0.f), 1.f);
        const float a = (c==0)?av.x:(c==1)?av.y:(c==2)?av.z:av.w;
        const float w = gate*a*a;               // adjs * (gate*adjs)
        wv[c] = w;
        rs[ii] += w;
        // sigmoid(logA - beta*log(-gamma/zeta)) = sigmoid(logA + 1.58261088)
        l0acc += 1.f/(1.f + expf(-(logA + 1.58261088f)));
      }
      *(float4*)(wsrow + jl) = make_float4(wv[0], wv[1], wv[2], wv[3]);
      outrow[jl+0] = wv[0]; outrow[jl+1] = wv[1];   // out+17 is 4B-aligned only
      outrow[jl+2] = wv[2]; outrow[jl+3] = wv[3];
    }
  }

  // row sums: reduce across the 16 jslot lanes (they share i)
  #pragma unroll
  for (int m = 1; m < 16; m <<= 1) {
    rs[0] += __shfl_xor(rs[0], m, 16);
    rs[1] += __shfl_xor(rs[1], m, 16);
  }
  if (jslot == 0) {
    atomicAdd(&row_sum[b*Nn + ia], rs[0]);
    atomicAdd(&row_sum[b*Nn + ib], rs[1]);
  }
  // l0: wave reduce, one atomic per wave
  #pragma unroll
  for (int m = 1; m < 64; m <<= 1) l0acc += __shfl_xor(l0acc, m, 64);
  if ((t & 63) == 0) atomicAdd(l0_sum, l0acc);
}

// Generic tiled f32 GEMM: C[b] = op(A[b] @ B[b]); 64x64 tile, 4x4 microtile.
__global__ __launch_bounds__(256) void gemm_tile(
    const float* __restrict__ A, const float* __restrict__ B, float* __restrict__ C,
    int M, int Nd, int K, long sAb, long sBb, long sCb,
    const float* __restrict__ rowsum, int rs_stride,
    const float* __restrict__ bias, int do_relu)
{
  const int bb = blockIdx.z;
  const float* Ab = A + (long)bb*sAb;
  const float* Bb = B + (long)bb*sBb;
  float* Cb = C + (long)bb*sCb;
  const int mt = blockIdx.y*64;
  const int nt = blockIdx.x*64;
  const int tid = threadIdx.x;
  const int tx = tid & 15, ty = tid >> 4;
  __shared__ float As[16][65];
  __shared__ float Bs[16][64];
  float c[4][4] = {};
  const int lm = tid >> 2;
  const int lk = (tid & 3)*4;
  const int lbn = tid & 63;
  const int lbk = tid >> 6;

  for (int kt = 0; kt < K; kt += 16) {
    const float4 av = *(const float4*)(Ab + (long)(mt+lm)*K + kt + lk);
    As[lk+0][lm] = av.x; As[lk+1][lm] = av.y; As[lk+2][lm] = av.z; As[lk+3][lm] = av.w;
    #pragma unroll
    for (int kk = 0; kk < 4; ++kk) {
      const int k = lbk*4 + kk;
      Bs[k][lbn] = Bb[(long)(kt+k)*Nd + nt + lbn];
    }
    __syncthreads();
    #pragma unroll
    for (int k = 0; k < 16; ++k) {
      const float a0 = As[k][ty*4+0], a1 = As[k][ty*4+1];
      const float a2 = As[k][ty*4+2], a3 = As[k][ty*4+3];
      const float b0 = Bs[k][tx*4+0], b1 = Bs[k][tx*4+1];
      const float b2v = Bs[k][tx*4+2], b3 = Bs[k][tx*4+3];
      c[0][0] += a0*b0; c[0][1] += a0*b1; c[0][2] += a0*b2v; c[0][3] += a0*b3;
      c[1][0] += a1*b0; c[1][1] += a1*b1; c[1][2] += a1*b2v; c[1][3] += a1*b3;
      c[2][0] += a2*b0; c[2][1] += a2*b1; c[2][2] += a2*b2v; c[2][3] += a2*b3;
      c[3][0] += a3*b0; c[3][1] += a3*b1; c[3][2] += a3*b2v; c[3][3] += a3*b3;
    }
    __syncthreads();
  }
  #pragma unroll
  for (int i = 0; i < 4; ++i) {
    const int m = mt + ty*4 + i;
    float scale = 1.f;
    if (rowsum) scale = 1.f/(rowsum[bb*rs_stride + m] + 1e-8f);
    #pragma unroll
    for (int j = 0; j < 4; ++j) {
      const int n = nt + tx*4 + j;
      float v = c[i][j]*scale;
      if (bias) v += bias[n];
      if (do_relu) v = fmaxf(v, 0.f);
      Cb[(long)m*Nd + n] = v;
    }
  }
}

// K5a: masked softmax over raw degree -> attn; zero graph_rep accumulators.
__global__ __launch_bounds__(256) void attn_kernel(
    const float* __restrict__ row_sum, const float* __restrict__ masks,
    float* __restrict__ attn, float* __restrict__ gr)
{
  const int b = blockIdx.x;
  const int t = threadIdx.x;
  __shared__ float red[256];
  const float m0 = masks[b*Nn + t], m1 = masks[b*Nn + t + 256];
  const float l0v = (m0 > 0.f) ? row_sum[b*Nn + t] : -1e9f;
  const float l1v = (m1 > 0.f) ? row_sum[b*Nn + t + 256] : -1e9f;
  red[t] = fmaxf(l0v, l1v); __syncthreads();
  for (int s = 128; s > 0; s >>= 1) { if (t < s) red[t] = fmaxf(red[t], red[t+s]); __syncthreads(); }
  const float mx = red[0];
  __syncthreads();
  const float ev0 = expf(l0v - mx), ev1 = expf(l1v - mx);
  red[t] = ev0 + ev1; __syncthreads();
  for (int s = 128; s > 0; s >>= 1) { if (t < s) red[t] += red[t+s]; __syncthreads(); }
  const float sinv = 1.f/red[0];
  attn[b*Nn + t] = ev0*sinv;
  attn[b*Nn + t + 256] = ev1*sinv;
  gr[b*Hh + t] = 0.f;
}

// K5b: graph_rep[b,h] += sum over 64-node chunk of attn*h. 64 blocks.
__global__ __launch_bounds__(256) void pool_accum(
    const float* __restrict__ attn, const float* __restrict__ h,
    float* __restrict__ gr)
{
  const int ic = blockIdx.x, b = blockIdx.y;
  const int t = threadIdx.x;
  const int i0 = ic*64;
  float acc = 0.f;
  #pragma unroll 4
  for (int i2 = 0; i2 < 64; ++i2) {
    acc += attn[b*Nn + i0 + i2] * h[((long)(b*Nn + i0 + i2))*Hh + t];
  }
  atomicAdd(&gr[b*Hh + t], acc);
}

// K6: classifier head + spectral norm + losses. Single block.
__global__ __launch_bounds__(256) void classifier_kernel(
    const float* __restrict__ gr, const float* __restrict__ W1c,
    const float* __restrict__ b1c, const float* __restrict__ ln_g,
    const float* __restrict__ ln_b, const float* __restrict__ W2c,
    const float* __restrict__ b2c, const float* __restrict__ u_sn,
    const int* __restrict__ labels, const float* __restrict__ l0_sum,
    float* __restrict__ out)
{
  const int t = threadIdx.x;
  __shared__ float grs[2048];
  __shared__ float z[8][128];
  __shared__ float red[256];
  __shared__ float vv[128];
  __shared__ float mu_s[8], ri_s[8];
  __shared__ float lg[16];
  for (int p = t; p < 2048; p += 256) grs[p] = gr[p];
  __syncthreads();
  #pragma unroll
  for (int p = 0; p < 4; ++p) {
    const int idx = t + p*256;
    const int b = idx >> 7, o = idx & 127;
    float acc = b1c[o];
    for (int d = 0; d < 256; ++d) acc += grs[b*256 + d]*W1c[d*128 + o];
    z[b][o] = fmaxf(acc, 0.f);
  }
  __syncthreads();
  if (t < 8) {
    float mu = 0.f;
    for (int o = 0; o < 128; ++o) mu += z[t][o];
    mu *= (1.f/128.f);
    float var = 0.f;
    for (int o = 0; o < 128; ++o) { const float d = z[t][o]-mu; var += d*d; }
    var *= (1.f/128.f);
    mu_s[t] = mu; ri_s[t] = rsqrtf(var + 1e-5f);
  }
  const float u0 = u_sn[0], u1 = u_sn[1];
  float vt = 0.f;
  if (t < 128) { vt = W2c[2*t]*u0 + W2c[2*t+1]*u1; vv[t] = vt; }
  red[t] = (t < 128) ? vt*vt : 0.f;
  __syncthreads();
  for (int s = 128; s > 0; s >>= 1) { if (t < s) red[t] += red[t+s]; __syncthreads(); }
  const float vninv = 1.f/fmaxf(sqrtf(red[0]), 1e-12f);
  __syncthreads();
  red[t] = (t < 128) ? W2c[2*t]*vv[t]*vninv : 0.f;
  __syncthreads();
  for (int s = 128; s > 0; s >>= 1) { if (t < s) red[t] += red[t+s]; __syncthreads(); }
  const float u20 = red[0];
  __syncthreads();
  red[t] = (t < 128) ? W2c[2*t+1]*vv[t]*vninv : 0.f;
  __syncthreads();
  for (int s = 128; s > 0; s >>= 1) { if (t < s) red[t] += red[t+s]; __syncthreads(); }
  const float u21 = red[0];
  __syncthreads();
  const float uninv = 1.f/fmaxf(sqrtf(u20*u20 + u21*u21), 1e-12f);
  const float u2n0 = u20*uninv, u2n1 = u21*uninv;
  red[t] = (t < 128) ? vv[t]*vninv*(W2c[2*t]*u2n0 + W2c[2*t+1]*u2n1) : 0.f;
  __syncthreads();
  for (int s = 128; s > 0; s >>= 1) { if (t < s) red[t] += red[t+s]; __syncthreads(); }
  const float sinv = 1.f/red[0];
  __syncthreads();
  if (t < 16) {
    const int b = t >> 1, c = t & 1;
    const float mu = mu_s[b], ri = ri_s[b];
    float acc = 0.f;
    for (int o = 0; o < 128; ++o) {
      const float zln = (z[b][o]-mu)*ri*ln_g[o] + ln_b[o];
      acc += zln*W2c[2*o + c];
    }
    const float lgv = acc*sinv + b2c[c];
    lg[t] = lgv;
    out[t] = lgv;
  }
  __syncthreads();
  if (t == 0) {
    float closs = 0.f;
    for (int b = 0; b < 8; ++b) {
      const float a0 = lg[2*b], a1 = lg[2*b+1];
      const float m = fmaxf(a0, a1);
      const float lse = m + logf(expf(a0-m) + expf(a1-m));
      closs += lse - lg[2*b + labels[b]];
    }
    closs *= (1.f/8.f);
    out[16] = closs + 0.01f*l0_sum[0];
  }
}

extern "C" void kernel_launch(void* const* d_in, const int* in_sizes, int n_in,
                              void* d_out, int out_size, void* d_ws, size_t ws_size,
                              hipStream_t stream) {
  const float* node_feat = (const float*)d_in[0];
  const int*   labels    = (const int*)d_in[1];
  const float* adjs      = (const float*)d_in[2];
  const float* masks     = (const float*)d_in[3];
  const float* Wa        = (const float*)d_in[4];
  const float* Wb        = (const float*)d_in[5];
  const float* be        = (const float*)d_in[6];
  const float* W2e       = (const float*)d_in[7];
  const float* b2e       = (const float*)d_in[8];
  const float* Wconv     = (const float*)d_in[9];
  const float* bconv     = (const float*)d_in[10];
  const float* W1c       = (const float*)d_in[11];
  const float* b1c       = (const float*)d_in[12];
  const float* ln_g      = (const float*)d_in[13];
  const float* ln_b      = (const float*)d_in[14];
  const float* W2c       = (const float*)d_in[15];
  const float* b2c       = (const float*)d_in[16];
  const float* u_sn      = (const float*)d_in[17];

  float* out = (float*)d_out;
  float* ws  = (float*)d_ws;
  float* nf      = ws + WS_NF;
  float* e1      = ws + WS_E1;
  float* e2      = ws + WS_E2;
  float* wadj    = ws + WS_WADJ;
  float* row_sum = ws + WS_RS;
  float* l0s     = ws + WS_L0;
  float* h_agg   = ws + WS_HAGG;
  float* h       = ws + WS_H;
  float* gr      = ws + WS_GR;
  float* attn    = ws + WS_E1;   // reuse: e1 dead after edge_kernel

  norm_e12_kernel<<<Bsz*Nn, 256, 0, stream>>>(node_feat, Wa, Wb, be, nf, e1, e2,
                                              row_sum, l0s);
  edge_kernel<<<dim3(Nn/128, Nn/32, Bsz), 256, 0, stream>>>(
      e1, e2, W2e, b2e, adjs, out + 17, wadj, row_sum, l0s);
  // h_agg[b] = (wadj[b]/rowsum) @ nf[b]
  gemm_tile<<<dim3(Nn/64, Nn/64, Bsz), 256, 0, stream>>>(
      wadj, nf, h_agg, Nn, Dd, Nn,
      (long)Nn*Nn, (long)Nn*Dd, (long)Nn*Dd, row_sum, Nn, nullptr, 0);
  // h = relu(h_agg @ Wconv + bconv), flat M = 4096
  gemm_tile<<<dim3(Hh/64, (Bsz*Nn)/64, 1), 256, 0, stream>>>(
      h_agg, Wconv, h, Bsz*Nn, Hh, Dd,
      0, 0, 0, nullptr, 0, bconv, 1);
  attn_kernel<<<Bsz, 256, 0, stream>>>(row_sum, masks, attn, gr);
  pool_accum<<<dim3(8, Bsz), 256, 0, stream>>>(attn, h, gr);
  classifier_kernel<<<1, 256, 0, stream>>>(gr, W1c, b1c, ln_g, ln_b, W2c, b2c,
                                           u_sn, labels, l0s, out);
}

// Round 3
// 218.656 us; speedup vs baseline: 1.4087x; 1.2682x over previous
//
#include <hip/hip_runtime.h>

// ---------------------------------------------------------------------------
// ImprovedEdgeGNN forward — MI355X
// Sizes: B=8, N=512, D=512, H=256, E=32, C=2
// out layout: [0:16) logits [8,2], [16] total_loss, [17:17+8*512*512) wadj
// R3: all GEMMs -> bf16 MFMA (16x16x32) with k-packed LDS layouts
//     (conflict-free ds_read_b128 frag loads); octet normalize kernel.
// ---------------------------------------------------------------------------

#define Bsz 8
#define Nn  512
#define Dd  512
#define Hh  256
#define Ee  32

// ws offsets (floats)
#define WS_NFB    0L          // nf bf16 row-major [8*512][512]      (1,048,576 f)
#define WS_NFPK   1048576L    // nf bf16 k-packed per batch          (1,048,576 f)
#define WS_E1     2097152L    // [4096][32] f32 (be folded)          (131,072 f)
#define WS_E2     2228224L    // [4096][32] f32                      (131,072 f)
#define WS_WADJB  2359296L    // wadj bf16 row-major [8][512][512]   (1,048,576 f)
#define WS_RS     3407872L    // [4096] raw row sums (= imp)
#define WS_L0     3411968L    // [1]
#define WS_HAGGB  3411976L    // h_agg bf16 row-major [4096][512]    (1,048,576 f)
#define WS_H      4460552L    // h f32 [4096][256]                   (1,048,576 f)
#define WS_GR     5509128L    // [8][256]
#define WS_ATTN   5511176L    // [8][512]
#define WS_WCPK   5515272L    // Wconv bf16 k-packed [64][256][8]    (65,536 f)
#define WS_WABPK  5580808L    // [Wa|Wb] bf16 k-packed [64][64][8]   (16,384 f)

typedef __bf16 bf16x8 __attribute__((ext_vector_type(8)));
typedef float  f32x4  __attribute__((ext_vector_type(4)));

__device__ inline ushort f2bf(float f) {
  union { float f; unsigned u; } c; c.f = f;
  return (ushort)((c.u + 0x7fffu + ((c.u >> 16) & 1u)) >> 16);
}

// ---------------------------------------------------------------------------
// K0: pack weights to bf16 k-packed granules [(K/8)][N][8].
// Wconv: 512x256 -> 16384 granules; Wa|Wb: 512x(32|32) -> 4096 granules.
__global__ __launch_bounds__(256) void pack_weights(
    const float* __restrict__ Wconv, const float* __restrict__ Wa,
    const float* __restrict__ Wb, ushort* __restrict__ wcpk,
    ushort* __restrict__ wabpk)
{
  const int g = blockIdx.x*256 + threadIdx.x;
  if (g < 16384) {
    const int k8 = g >> 8, n = g & 255;
    ushort tmp[8];
    #pragma unroll
    for (int j = 0; j < 8; ++j) tmp[j] = f2bf(Wconv[(k8*8 + j)*Hh + n]);
    #pragma unroll
    for (int j = 0; j < 8; ++j) wcpk[(long)g*8 + j] = tmp[j];
  } else if (g < 16384 + 4096) {
    const int gg = g - 16384;
    const int k8 = gg >> 6, n = gg & 63;
    const float* W = (n < 32) ? Wa : Wb;
    const int e = n & 31;
    ushort tmp[8];
    #pragma unroll
    for (int j = 0; j < 8; ++j) tmp[j] = f2bf(W[(k8*8 + j)*Ee + e]);
    #pragma unroll
    for (int j = 0; j < 8; ++j) wabpk[(long)gg*8 + j] = tmp[j];
  }
}

// ---------------------------------------------------------------------------
// K1: normalize 8 rows per block; emit nf bf16 row-major + nf bf16 k-packed.
// Also zeroes row_sum (and l0_sum from block 0).
__global__ __launch_bounds__(256) void norm_octet(
    const float* __restrict__ nfeat, ushort* __restrict__ nfb,
    ushort* __restrict__ nfpk, float* __restrict__ row_sum,
    float* __restrict__ l0_sum)
{
  const int r0 = blockIdx.x*8;     // global row (b*512 + i), octet-aligned
  const int t = threadIdx.x;
  __shared__ float xs[8][512];
  __shared__ float sc[8];

  #pragma unroll
  for (int p = 0; p < 4; ++p) {
    const int off = t + p*256;          // float4 index, 0..1023
    const int row = off >> 7, d4 = off & 127;
    const float4 v = *(const float4*)(nfeat + ((long)(r0+row))*Dd + d4*4);
    *(float4*)(&xs[row][d4*4]) = v;
  }
  if (t < 8) row_sum[r0 + t] = 0.f;
  if (blockIdx.x == 0 && t == 0) *l0_sum = 0.f;
  __syncthreads();

  // 32 threads per row reduce
  {
    const int row = t >> 5, lane = t & 31;
    float s = 0.f;
    #pragma unroll
    for (int j = 0; j < 16; ++j) { const float x = xs[row][lane + j*32]; s += x*x; }
    #pragma unroll
    for (int m = 1; m < 32; m <<= 1) s += __shfl_xor(s, m, 32);
    if (lane == 0) sc[row] = 1.f / fmaxf(sqrtf(s), 1e-12f);
  }
  __syncthreads();

  // row-major bf16 out
  #pragma unroll
  for (int p = 0; p < 4; ++p) {
    const int off = t + p*256;
    const int row = off >> 7, d4 = off & 127;
    const float s = sc[row];
    ushort4 o;
    o.x = f2bf(xs[row][d4*4+0]*s); o.y = f2bf(xs[row][d4*4+1]*s);
    o.z = f2bf(xs[row][d4*4+2]*s); o.w = f2bf(xs[row][d4*4+3]*s);
    *(ushort4*)(nfb + ((long)(r0+row))*Dd + d4*4) = o;
  }
  // k-packed out: granule d holds rows r0..r0+7 at column d.
  const int batch = r0 >> 9;
  const int oct_b = (r0 >> 3) & 63;
  #pragma unroll
  for (int p = 0; p < 2; ++p) {
    const int d = t + p*256;
    ushort tmp[8];
    #pragma unroll
    for (int j = 0; j < 8; ++j) tmp[j] = f2bf(xs[j][d]*sc[j]);
    *(uint4*)(nfpk + ((long)batch*262144 + ((long)oct_b*512 + d)*8)) = *(uint4*)tmp;
  }
}

// ---------------------------------------------------------------------------
// MFMA GEMM. A: bf16 row-major [M][K] (k-contig). B: bf16 k-packed
// [(K/8)][N][8]. LDS tiles stored as granules [kq][rows][8] so frag loads
// are single conflict-free ds_read_b128 per lane.
// OP 0: C_bf16 = (A@B) * 1/(rowsum[bb*M+row]+1e-8)        (gemm1 -> h_agg)
// OP 1: C_f32  = relu(A@B + bias[col])                    (gemm2 -> h)
// OP 2: col<32 -> e1=acc+be[col]; else e2=acc             (e12)
template<int OP, int BM, int BN>
__global__ __launch_bounds__(256) void mfma_gemm(
    const ushort* __restrict__ A, const ushort* __restrict__ Bpk,
    int M, int N, int K, long sA, long sB, long sC,
    const float* __restrict__ aux1, float* __restrict__ C,
    ushort* __restrict__ Cb, float* __restrict__ C2)
{
  constexpr int FM = BM/32, FN = BN/32;
  const int bb = blockIdx.z;
  const int m0 = blockIdx.y*BM, n0 = blockIdx.x*BN;
  const int t = threadIdx.x;
  const int lane = t & 63, l15 = lane & 15, quad = lane >> 4;
  const int wr = (t >> 6) & 1, wc = t >> 7;

  __shared__ ushort As[32*BM];
  __shared__ ushort Bs[32*BN];

  const ushort* Ab = A + bb*sA;
  const ushort* Bb = Bpk + bb*sB;

  f32x4 acc[FM][FN];
  #pragma unroll
  for (int i = 0; i < FM; ++i)
    #pragma unroll
    for (int j = 0; j < FN; ++j) acc[i][j] = (f32x4){0.f,0.f,0.f,0.f};

  for (int k0 = 0; k0 < K; k0 += 32) {
    #pragma unroll
    for (int r = 0; r < BM/64; ++r) {
      const int g = t + r*256;
      const int m = g >> 2, kq = g & 3;
      const uint4 v = *(const uint4*)(Ab + (long)(m0+m)*K + k0 + kq*8);
      *(uint4*)(As + ((kq*BM + m)*8)) = v;
    }
    #pragma unroll
    for (int r = 0; r < BN/64; ++r) {
      const int g = t + r*256;
      const int n = g % BN, kq = g / BN;
      const uint4 v = *(const uint4*)(Bb + ((long)((k0>>3) + kq)*N + n0 + n)*8);
      *(uint4*)(Bs + ((kq*BN + n)*8)) = v;
    }
    __syncthreads();
    bf16x8 af[FM], bfr[FN];
    #pragma unroll
    for (int fm = 0; fm < FM; ++fm)
      af[fm] = *(const bf16x8*)(As + (quad*BM + wr*(BM/2) + fm*16 + l15)*8);
    #pragma unroll
    for (int fn = 0; fn < FN; ++fn)
      bfr[fn] = *(const bf16x8*)(Bs + (quad*BN + wc*(BN/2) + fn*16 + l15)*8);
    #pragma unroll
    for (int fm = 0; fm < FM; ++fm)
      #pragma unroll
      for (int fn = 0; fn < FN; ++fn)
        acc[fm][fn] = __builtin_amdgcn_mfma_f32_16x16x32_bf16(
            af[fm], bfr[fn], acc[fm][fn], 0, 0, 0);
    __syncthreads();
  }

  #pragma unroll
  for (int fm = 0; fm < FM; ++fm) {
    #pragma unroll
    for (int fn = 0; fn < FN; ++fn) {
      const int col = n0 + wc*(BN/2) + fn*16 + l15;
      #pragma unroll
      for (int r = 0; r < 4; ++r) {
        const int row = m0 + wr*(BM/2) + fm*16 + quad*4 + r;
        float v = acc[fm][fn][r];
        if (OP == 0) {
          const float s = 1.f/(aux1[bb*M + row] + 1e-8f);
          Cb[bb*sC + (long)row*N + col] = f2bf(v*s);
        } else if (OP == 1) {
          v += aux1[col];
          C[(long)row*N + col] = fmaxf(v, 0.f);
        } else {
          if (col < 32) C[(long)row*32 + col] = v + aux1[col];
          else          C2[(long)row*32 + (col-32)] = v;
        }
      }
    }
  }
}

// ---------------------------------------------------------------------------
// K2: tiled edge scoring. Block = (b, 32-row i-tile, 128-col j-tile).
__global__ __launch_bounds__(256) void edge_kernel(
    const float* __restrict__ e1, const float* __restrict__ e2,
    const float* __restrict__ W2e, const float* __restrict__ b2e,
    const float* __restrict__ adjs, float* __restrict__ out_wadj,
    ushort* __restrict__ wadj_b, float* __restrict__ row_sum,
    float* __restrict__ l0_sum)
{
  const int b  = blockIdx.z;
  const int i0 = blockIdx.y * 32;
  const int j0 = blockIdx.x * 128;
  const int t  = threadIdx.x;

  __shared__ float e2s[32*132];

  #pragma unroll
  for (int itr = 0; itr < 4; ++itr) {
    const int idx = t + itr*256;
    const int kq = idx & 7, jg = idx >> 3;
    const float4 v = *(const float4*)(e2 + ((long)(b*Nn + j0 + jg))*Ee + kq*4);
    e2s[(kq*4+0)*132 + jg] = v.x;
    e2s[(kq*4+1)*132 + jg] = v.y;
    e2s[(kq*4+2)*132 + jg] = v.z;
    e2s[(kq*4+3)*132 + jg] = v.w;
  }

  const int pair  = t >> 4;
  const int jslot = t & 15;
  const int ia = i0 + pair*2;
  const int ib = ia + 1;
  const int ja = jslot*4;
  const int jb = ja + 64;

  float e1af[32], e1bf[32], w2f[32];
  #pragma unroll
  for (int q = 0; q < 8; ++q) {
    *(float4*)(&e1af[q*4]) = *(const float4*)(e1 + ((long)(b*Nn + ia))*Ee + q*4);
    *(float4*)(&e1bf[q*4]) = *(const float4*)(e1 + ((long)(b*Nn + ib))*Ee + q*4);
    *(float4*)(&w2f[q*4])  = *(const float4*)(W2e + q*4);
  }
  const float b2 = b2e[0];
  __syncthreads();

  float acc[2][8] = {};
  #pragma unroll
  for (int k = 0; k < 32; ++k) {
    const float4 va = *(const float4*)(e2s + k*132 + ja);
    const float4 vb = *(const float4*)(e2s + k*132 + jb);
    const float w = w2f[k];
    const float ea = e1af[k], eb = e1bf[k];
    acc[0][0] += fmaxf(ea+va.x, 0.f)*w;
    acc[0][1] += fmaxf(ea+va.y, 0.f)*w;
    acc[0][2] += fmaxf(ea+va.z, 0.f)*w;
    acc[0][3] += fmaxf(ea+va.w, 0.f)*w;
    acc[0][4] += fmaxf(ea+vb.x, 0.f)*w;
    acc[0][5] += fmaxf(ea+vb.y, 0.f)*w;
    acc[0][6] += fmaxf(ea+vb.z, 0.f)*w;
    acc[0][7] += fmaxf(ea+vb.w, 0.f)*w;
    acc[1][0] += fmaxf(eb+va.x, 0.f)*w;
    acc[1][1] += fmaxf(eb+va.y, 0.f)*w;
    acc[1][2] += fmaxf(eb+va.z, 0.f)*w;
    acc[1][3] += fmaxf(eb+va.w, 0.f)*w;
    acc[1][4] += fmaxf(eb+vb.x, 0.f)*w;
    acc[1][5] += fmaxf(eb+vb.y, 0.f)*w;
    acc[1][6] += fmaxf(eb+vb.z, 0.f)*w;
    acc[1][7] += fmaxf(eb+vb.w, 0.f)*w;
  }

  float rs[2] = {0.f, 0.f};
  float l0acc = 0.f;
  #pragma unroll
  for (int ii = 0; ii < 2; ++ii) {
    const int i = (ii == 0) ? ia : ib;
    const float* arow = adjs     + ((long)(b*Nn + i))*Nn + j0;
    ushort* bwrow     = wadj_b   + ((long)(b*Nn + i))*Nn + j0;
    float* outrow     = out_wadj + ((long)(b*Nn + i))*Nn + j0;
    #pragma unroll
    for (int h2 = 0; h2 < 2; ++h2) {
      const int jl = (h2 == 0) ? ja : jb;
      const float4 av = *(const float4*)(arow + jl);
      float wv[4];
      #pragma unroll
      for (int c = 0; c < 4; ++c) {
        const float logA = acc[ii][h2*4 + c] + b2;
        const float sg = 1.f/(1.f + expf(-logA));
        const float gate = fminf(fmaxf(sg*1.2f - 0.1f, 0.f), 1.f);
        const float a = (c==0)?av.x:(c==1)?av.y:(c==2)?av.z:av.w;
        const float w = gate*a*a;
        wv[c] = w;
        rs[ii] += w;
        l0acc += 1.f/(1.f + expf(-(logA + 1.58261088f)));
      }
      ushort4 bw;
      bw.x = f2bf(wv[0]); bw.y = f2bf(wv[1]); bw.z = f2bf(wv[2]); bw.w = f2bf(wv[3]);
      *(ushort4*)(bwrow + jl) = bw;
      outrow[jl+0] = wv[0]; outrow[jl+1] = wv[1];
      outrow[jl+2] = wv[2]; outrow[jl+3] = wv[3];
    }
  }

  #pragma unroll
  for (int m = 1; m < 16; m <<= 1) {
    rs[0] += __shfl_xor(rs[0], m, 16);
    rs[1] += __shfl_xor(rs[1], m, 16);
  }
  if (jslot == 0) {
    atomicAdd(&row_sum[b*Nn + ia], rs[0]);
    atomicAdd(&row_sum[b*Nn + ib], rs[1]);
  }
  #pragma unroll
  for (int m = 1; m < 64; m <<= 1) l0acc += __shfl_xor(l0acc, m, 64);
  if ((t & 63) == 0) atomicAdd(l0_sum, l0acc);
}

// ---------------------------------------------------------------------------
// K5a: masked softmax over raw degree -> attn; zero graph_rep accumulators.
__global__ __launch_bounds__(256) void attn_kernel(
    const float* __restrict__ row_sum, const float* __restrict__ masks,
    float* __restrict__ attn, float* __restrict__ gr)
{
  const int b = blockIdx.x;
  const int t = threadIdx.x;
  __shared__ float red[256];
  const float m0 = masks[b*Nn + t], m1 = masks[b*Nn + t + 256];
  const float l0v = (m0 > 0.f) ? row_sum[b*Nn + t] : -1e9f;
  const float l1v = (m1 > 0.f) ? row_sum[b*Nn + t + 256] : -1e9f;
  red[t] = fmaxf(l0v, l1v); __syncthreads();
  for (int s = 128; s > 0; s >>= 1) { if (t < s) red[t] = fmaxf(red[t], red[t+s]); __syncthreads(); }
  const float mx = red[0];
  __syncthreads();
  const float ev0 = expf(l0v - mx), ev1 = expf(l1v - mx);
  red[t] = ev0 + ev1; __syncthreads();
  for (int s = 128; s > 0; s >>= 1) { if (t < s) red[t] += red[t+s]; __syncthreads(); }
  const float sinv = 1.f/red[0];
  attn[b*Nn + t] = ev0*sinv;
  attn[b*Nn + t + 256] = ev1*sinv;
  gr[b*Hh + t] = 0.f;
}

// K5b: graph_rep[b,h] += sum over 64-node chunk of attn*h.
__global__ __launch_bounds__(256) void pool_accum(
    const float* __restrict__ attn, const float* __restrict__ h,
    float* __restrict__ gr)
{
  const int ic = blockIdx.x, b = blockIdx.y;
  const int t = threadIdx.x;
  const int i0 = ic*64;
  float acc = 0.f;
  #pragma unroll 4
  for (int i2 = 0; i2 < 64; ++i2) {
    acc += attn[b*Nn + i0 + i2] * h[((long)(b*Nn + i0 + i2))*Hh + t];
  }
  atomicAdd(&gr[b*Hh + t], acc);
}

// ---------------------------------------------------------------------------
// K6: classifier head + spectral norm + losses. Single block.
__global__ __launch_bounds__(256) void classifier_kernel(
    const float* __restrict__ gr, const float* __restrict__ W1c,
    const float* __restrict__ b1c, const float* __restrict__ ln_g,
    const float* __restrict__ ln_b, const float* __restrict__ W2c,
    const float* __restrict__ b2c, const float* __restrict__ u_sn,
    const int* __restrict__ labels, const float* __restrict__ l0_sum,
    float* __restrict__ out)
{
  const int t = threadIdx.x;
  __shared__ float grs[2048];
  __shared__ float z[8][128];
  __shared__ float red[256];
  __shared__ float vv[128];
  __shared__ float mu_s[8], ri_s[8];
  __shared__ float lg[16];
  for (int p = t; p < 2048; p += 256) grs[p] = gr[p];
  __syncthreads();
  #pragma unroll
  for (int p = 0; p < 4; ++p) {
    const int idx = t + p*256;
    const int b = idx >> 7, o = idx & 127;
    float acc = b1c[o];
    for (int d = 0; d < 256; ++d) acc += grs[b*256 + d]*W1c[d*128 + o];
    z[b][o] = fmaxf(acc, 0.f);
  }
  __syncthreads();
  if (t < 8) {
    float mu = 0.f;
    for (int o = 0; o < 128; ++o) mu += z[t][o];
    mu *= (1.f/128.f);
    float var = 0.f;
    for (int o = 0; o < 128; ++o) { const float d = z[t][o]-mu; var += d*d; }
    var *= (1.f/128.f);
    mu_s[t] = mu; ri_s[t] = rsqrtf(var + 1e-5f);
  }
  const float u0 = u_sn[0], u1 = u_sn[1];
  float vt = 0.f;
  if (t < 128) { vt = W2c[2*t]*u0 + W2c[2*t+1]*u1; vv[t] = vt; }
  red[t] = (t < 128) ? vt*vt : 0.f;
  __syncthreads();
  for (int s = 128; s > 0; s >>= 1) { if (t < s) red[t] += red[t+s]; __syncthreads(); }
  const float vninv = 1.f/fmaxf(sqrtf(red[0]), 1e-12f);
  __syncthreads();
  red[t] = (t < 128) ? W2c[2*t]*vv[t]*vninv : 0.f;
  __syncthreads();
  for (int s = 128; s > 0; s >>= 1) { if (t < s) red[t] += red[t+s]; __syncthreads(); }
  const float u20 = red[0];
  __syncthreads();
  red[t] = (t < 128) ? W2c[2*t+1]*vv[t]*vninv : 0.f;
  __syncthreads();
  for (int s = 128; s > 0; s >>= 1) { if (t < s) red[t] += red[t+s]; __syncthreads(); }
  const float u21 = red[0];
  __syncthreads();
  const float uninv = 1.f/fmaxf(sqrtf(u20*u20 + u21*u21), 1e-12f);
  const float u2n0 = u20*uninv, u2n1 = u21*uninv;
  red[t] = (t < 128) ? vv[t]*vninv*(W2c[2*t]*u2n0 + W2c[2*t+1]*u2n1) : 0.f;
  __syncthreads();
  for (int s = 128; s > 0; s >>= 1) { if (t < s) red[t] += red[t+s]; __syncthreads(); }
  const float sinv = 1.f/red[0];
  __syncthreads();
  if (t < 16) {
    const int b = t >> 1, c = t & 1;
    const float mu = mu_s[b], ri = ri_s[b];
    float acc = 0.f;
    for (int o = 0; o < 128; ++o) {
      const float zln = (z[b][o]-mu)*ri*ln_g[o] + ln_b[o];
      acc += zln*W2c[2*o + c];
    }
    const float lgv = acc*sinv + b2c[c];
    lg[t] = lgv;
    out[t] = lgv;
  }
  __syncthreads();
  if (t == 0) {
    float closs = 0.f;
    for (int b = 0; b < 8; ++b) {
      const float a0 = lg[2*b], a1 = lg[2*b+1];
      const float m = fmaxf(a0, a1);
      const float lse = m + logf(expf(a0-m) + expf(a1-m));
      closs += lse - lg[2*b + labels[b]];
    }
    closs *= (1.f/8.f);
    out[16] = closs + 0.01f*l0_sum[0];
  }
}

extern "C" void kernel_launch(void* const* d_in, const int* in_sizes, int n_in,
                              void* d_out, int out_size, void* d_ws, size_t ws_size,
                              hipStream_t stream) {
  const float* node_feat = (const float*)d_in[0];
  const int*   labels    = (const int*)d_in[1];
  const float* adjs      = (const float*)d_in[2];
  const float* masks     = (const float*)d_in[3];
  const float* Wa        = (const float*)d_in[4];
  const float* Wb        = (const float*)d_in[5];
  const float* be        = (const float*)d_in[6];
  const float* W2e       = (const float*)d_in[7];
  const float* b2e       = (const float*)d_in[8];
  const float* Wconv     = (const float*)d_in[9];
  const float* bconv     = (const float*)d_in[10];
  const float* W1c       = (const float*)d_in[11];
  const float* b1c       = (const float*)d_in[12];
  const float* ln_g      = (const float*)d_in[13];
  const float* ln_b      = (const float*)d_in[14];
  const float* W2c       = (const float*)d_in[15];
  const float* b2c       = (const float*)d_in[16];
  const float* u_sn      = (const float*)d_in[17];

  float* out = (float*)d_out;
  float* ws  = (float*)d_ws;
  ushort* nfb    = (ushort*)(ws + WS_NFB);
  ushort* nfpk   = (ushort*)(ws + WS_NFPK);
  float*  e1     = ws + WS_E1;
  float*  e2     = ws + WS_E2;
  ushort* wadjb  = (ushort*)(ws + WS_WADJB);
  float*  row_sum= ws + WS_RS;
  float*  l0s    = ws + WS_L0;
  ushort* haggb  = (ushort*)(ws + WS_HAGGB);
  float*  h      = ws + WS_H;
  float*  gr     = ws + WS_GR;
  float*  attn   = ws + WS_ATTN;
  ushort* wcpk   = (ushort*)(ws + WS_WCPK);
  ushort* wabpk  = (ushort*)(ws + WS_WABPK);

  pack_weights<<<80, 256, 0, stream>>>(Wconv, Wa, Wb, wcpk, wabpk);
  norm_octet<<<Bsz*Nn/8, 256, 0, stream>>>(node_feat, nfb, nfpk, row_sum, l0s);
  // e1|e2 = nf @ [Wa|Wb]  (M=4096, N=64, K=512)
  mfma_gemm<2, 128, 64><<<dim3(1, 32, 1), 256, 0, stream>>>(
      nfb, wabpk, 4096, 64, 512, 0, 0, 0, be, e1, nullptr, e2);
  edge_kernel<<<dim3(Nn/128, Nn/32, Bsz), 256, 0, stream>>>(
      e1, e2, W2e, b2e, adjs, out + 17, wadjb, row_sum, l0s);
  // h_agg[b] = (wadj[b]/rowsum) @ nf[b]  (batched 512x512x512)
  mfma_gemm<0, 64, 128><<<dim3(Nn/128, Nn/64, Bsz), 256, 0, stream>>>(
      wadjb, nfpk, 512, 512, 512, 262144L, 262144L, 262144L,
      row_sum, nullptr, haggb, nullptr);
  // h = relu(h_agg @ Wconv + bconv)  (M=4096, N=256, K=512)
  mfma_gemm<1, 64, 128><<<dim3(Hh/128, 4096/64, 1), 256, 0, stream>>>(
      haggb, wcpk, 4096, 256, 512, 0, 0, 0, bconv, h, nullptr, nullptr);
  attn_kernel<<<Bsz, 256, 0, stream>>>(row_sum, masks, attn, gr);
  pool_accum<<<dim3(8, Bsz), 256, 0, stream>>>(attn, h, gr);
  classifier_kernel<<<1, 256, 0, stream>>>(gr, W1c, b1c, ln_g, ln_b, W2c, b2c,
                                           u_sn, labels, l0s, out);
}

// Round 4
// 201.804 us; speedup vs baseline: 1.5263x; 1.0835x over previous
//
#include <hip/hip_runtime.h>

// ---------------------------------------------------------------------------
// ImprovedEdgeGNN forward — MI355X
// Sizes: B=8, N=512, D=512, H=256, E=32, C=2
// out layout: [0:16) logits [8,2], [16] total_loss, [17:17+8*512*512) wadj
// R4: 6 launches (was 9). norm+e12 fused (MFMA in-kernel, inline W convert),
//     pipelined mfma_gemm64 with VGPR prefetch + padded LDS granules,
//     attn fused into pool.
// ---------------------------------------------------------------------------

#define Bsz 8
#define Nn  512
#define Dd  512
#define Hh  256
#define Ee  32

// ws offsets (floats)
#define WS_NFPK   0L          // nf bf16 k-packed per batch [8][64oct][512][8]  (1,048,576 f)
#define WS_E1     1048576L    // [4096][32] f32 (be folded)                     (131,072 f)
#define WS_E2     1179648L    // [4096][32] f32                                 (131,072 f)
#define WS_WADJB  1310720L    // wadj bf16 row-major [8][512][512]              (524,288 f)
#define WS_RS     1835008L    // [4096] raw row sums (= imp)
#define WS_L0     1839104L    // [8]
#define WS_HAGGB  1839112L    // h_agg bf16 row-major [4096][512]               (524,288 f)
#define WS_H      2363400L    // h f32 [4096][256]                              (1,048,576 f)
#define WS_GR     3411976L    // [8][256]

typedef __bf16 bf16x8 __attribute__((ext_vector_type(8)));
typedef float  f32x4  __attribute__((ext_vector_type(4)));

__device__ inline ushort f2bf(float f) {
  union { float f; unsigned u; } c; c.f = f;
  return (ushort)((c.u + 0x7fffu + ((c.u >> 16) & 1u)) >> 16);
}

// ---------------------------------------------------------------------------
// K1: fused normalize + e1|e2 MFMA GEMM. 256 blocks x 16 rows.
//  - rows L2-normalized in registers (f32), bf16 granules -> LDS A-tile
//    (granule stride 17: staging 2-way conflicts max, frag reads clean)
//  - nfpk (k-packed nf for gemm1's B) written via LDS transpose
//  - e1|e2 = nf @ [Wa|Wb] via one 16x16x32 MFMA chain per wave, W converted
//    f32->bf16 inline during B staging
//  - zeroes row_sum rows (this block), gr + l0 (block 0)
__global__ __launch_bounds__(256) void norm_e12_fused(
    const float* __restrict__ nfeat, const float* __restrict__ Wa,
    const float* __restrict__ Wb, const float* __restrict__ be,
    ushort* __restrict__ nfpk, float* __restrict__ e1, float* __restrict__ e2,
    float* __restrict__ row_sum, float* __restrict__ gr,
    float* __restrict__ l0_sum)
{
  const int blk = blockIdx.x;
  const int r0 = blk*16;               // global row base (b*512 + local)
  const int b = r0 >> 9;
  const int t = threadIdx.x;
  const int r = t >> 4;                // local row 0..15
  const int seg = t & 15;              // 32-col segment

  __shared__ ushort As[(63*17 + 15 + 1)*8];   // granule (kq*17 + row)*8
  __shared__ ushort Bs[4*64*8];               // granule (kq2*64 + n)*8

  // ---- phase 1: load 32 f32/thread, row norm, bf16 granules to LDS ----
  float4 v[8];
  const float* src = nfeat + (long)(r0 + r)*Dd + seg*32;
  #pragma unroll
  for (int i = 0; i < 8; ++i) v[i] = *(const float4*)(src + i*4);
  float s = 0.f;
  #pragma unroll
  for (int i = 0; i < 8; ++i)
    s += v[i].x*v[i].x + v[i].y*v[i].y + v[i].z*v[i].z + v[i].w*v[i].w;
  #pragma unroll
  for (int m = 1; m < 16; m <<= 1) s += __shfl_xor(s, m, 16);
  const float sc = 1.f / fmaxf(sqrtf(s), 1e-12f);
  #pragma unroll
  for (int q = 0; q < 4; ++q) {
    ushort tmp[8];
    const float4 a = v[2*q], bq = v[2*q+1];
    tmp[0]=f2bf(a.x*sc);  tmp[1]=f2bf(a.y*sc);  tmp[2]=f2bf(a.z*sc);  tmp[3]=f2bf(a.w*sc);
    tmp[4]=f2bf(bq.x*sc); tmp[5]=f2bf(bq.y*sc); tmp[6]=f2bf(bq.z*sc); tmp[7]=f2bf(bq.w*sc);
    *(uint4*)(As + ((seg*4 + q)*17 + r)*8) = *(uint4*)tmp;
  }
  if (t < 16) row_sum[r0 + t] = 0.f;
  if (blk == 0) {
    for (int p = t; p < Bsz*Hh; p += 256) gr[p] = 0.f;
    if (t == 0) *l0_sum = 0.f;
  }
  __syncthreads();

  // ---- phase 2: nfpk global write (LDS transpose) ----
  // granule g: oct (0/1) x column d; holds rows oct*8..+7 at column d.
  #pragma unroll
  for (int p = 0; p < 4; ++p) {
    const int g = t + p*256;
    const int oct = g >> 9, d = g & 511;
    ushort tmp[8];
    #pragma unroll
    for (int j = 0; j < 8; ++j)
      tmp[j] = As[((d >> 3)*17 + oct*8 + j)*8 + (d & 7)];
    const long og = ((r0 & 511) >> 3) + oct;   // octet index within batch
    *(uint4*)(nfpk + ((long)b*262144 + (og*512 + d)*8)) = *(uint4*)tmp;
  }

  // ---- phase 3: e1|e2 MFMA. wave w -> output cols w*16..w*16+15 ----
  const int lane = t & 63, l15 = lane & 15, quad = lane >> 4;
  const int w = t >> 6;
  f32x4 acc = {0.f, 0.f, 0.f, 0.f};
  const int bn = t & 63, bkq = t >> 6;
  for (int k0 = 0; k0 < 512; k0 += 32) {
    ushort tmp[8];
    {
      const float* W = (bn < 32) ? Wa : Wb;
      const int col = bn & 31;
      #pragma unroll
      for (int j = 0; j < 8; ++j)
        tmp[j] = f2bf(W[(long)(k0 + bkq*8 + j)*Ee + col]);
    }
    __syncthreads();     // prior frag reads done before Bs overwrite
    *(uint4*)(Bs + (bkq*64 + bn)*8) = *(uint4*)tmp;
    __syncthreads();
    const bf16x8 af  = *(const bf16x8*)(As + (((k0 >> 3) + quad)*17 + l15)*8);
    const bf16x8 bfr = *(const bf16x8*)(Bs + (quad*64 + w*16 + l15)*8);
    acc = __builtin_amdgcn_mfma_f32_16x16x32_bf16(af, bfr, acc, 0, 0, 0);
  }
  const int col = w*16 + l15;
  #pragma unroll
  for (int rr = 0; rr < 4; ++rr) {
    const int row = r0 + quad*4 + rr;
    if (col < 32) e1[(long)row*Ee + col] = acc[rr] + be[col];
    else          e2[(long)row*Ee + (col - 32)] = acc[rr];
  }
}

// ---------------------------------------------------------------------------
// K2: tiled edge scoring. Block = (b, 32-row i-tile, 128-col j-tile).
__global__ __launch_bounds__(256) void edge_kernel(
    const float* __restrict__ e1, const float* __restrict__ e2,
    const float* __restrict__ W2e, const float* __restrict__ b2e,
    const float* __restrict__ adjs, float* __restrict__ out_wadj,
    ushort* __restrict__ wadj_b, float* __restrict__ row_sum,
    float* __restrict__ l0_sum)
{
  const int b  = blockIdx.z;
  const int i0 = blockIdx.y * 32;
  const int j0 = blockIdx.x * 128;
  const int t  = threadIdx.x;

  __shared__ float e2s[32*132];

  #pragma unroll
  for (int itr = 0; itr < 4; ++itr) {
    const int idx = t + itr*256;
    const int kq = idx & 7, jg = idx >> 3;
    const float4 v = *(const float4*)(e2 + ((long)(b*Nn + j0 + jg))*Ee + kq*4);
    e2s[(kq*4+0)*132 + jg] = v.x;
    e2s[(kq*4+1)*132 + jg] = v.y;
    e2s[(kq*4+2)*132 + jg] = v.z;
    e2s[(kq*4+3)*132 + jg] = v.w;
  }

  const int pair  = t >> 4;
  const int jslot = t & 15;
  const int ia = i0 + pair*2;
  const int ib = ia + 1;
  const int ja = jslot*4;
  const int jb = ja + 64;

  float e1af[32], e1bf[32], w2f[32];
  #pragma unroll
  for (int q = 0; q < 8; ++q) {
    *(float4*)(&e1af[q*4]) = *(const float4*)(e1 + ((long)(b*Nn + ia))*Ee + q*4);
    *(float4*)(&e1bf[q*4]) = *(const float4*)(e1 + ((long)(b*Nn + ib))*Ee + q*4);
    *(float4*)(&w2f[q*4])  = *(const float4*)(W2e + q*4);
  }
  const float b2 = b2e[0];
  __syncthreads();

  float acc[2][8] = {};
  #pragma unroll
  for (int k = 0; k < 32; ++k) {
    const float4 va = *(const float4*)(e2s + k*132 + ja);
    const float4 vb = *(const float4*)(e2s + k*132 + jb);
    const float w = w2f[k];
    const float ea = e1af[k], eb = e1bf[k];
    acc[0][0] += fmaxf(ea+va.x, 0.f)*w;
    acc[0][1] += fmaxf(ea+va.y, 0.f)*w;
    acc[0][2] += fmaxf(ea+va.z, 0.f)*w;
    acc[0][3] += fmaxf(ea+va.w, 0.f)*w;
    acc[0][4] += fmaxf(ea+vb.x, 0.f)*w;
    acc[0][5] += fmaxf(ea+vb.y, 0.f)*w;
    acc[0][6] += fmaxf(ea+vb.z, 0.f)*w;
    acc[0][7] += fmaxf(ea+vb.w, 0.f)*w;
    acc[1][0] += fmaxf(eb+va.x, 0.f)*w;
    acc[1][1] += fmaxf(eb+va.y, 0.f)*w;
    acc[1][2] += fmaxf(eb+va.z, 0.f)*w;
    acc[1][3] += fmaxf(eb+va.w, 0.f)*w;
    acc[1][4] += fmaxf(eb+vb.x, 0.f)*w;
    acc[1][5] += fmaxf(eb+vb.y, 0.f)*w;
    acc[1][6] += fmaxf(eb+vb.z, 0.f)*w;
    acc[1][7] += fmaxf(eb+vb.w, 0.f)*w;
  }

  float rs[2] = {0.f, 0.f};
  float l0acc = 0.f;
  #pragma unroll
  for (int ii = 0; ii < 2; ++ii) {
    const int i = (ii == 0) ? ia : ib;
    const float* arow = adjs     + ((long)(b*Nn + i))*Nn + j0;
    ushort* bwrow     = wadj_b   + ((long)(b*Nn + i))*Nn + j0;
    float* outrow     = out_wadj + ((long)(b*Nn + i))*Nn + j0;
    #pragma unroll
    for (int h2 = 0; h2 < 2; ++h2) {
      const int jl = (h2 == 0) ? ja : jb;
      const float4 av = *(const float4*)(arow + jl);
      float wv[4];
      #pragma unroll
      for (int c = 0; c < 4; ++c) {
        const float logA = acc[ii][h2*4 + c] + b2;
        const float sg = 1.f/(1.f + expf(-logA));
        const float gate = fminf(fmaxf(sg*1.2f - 0.1f, 0.f), 1.f);
        const float a = (c==0)?av.x:(c==1)?av.y:(c==2)?av.z:av.w;
        const float w = gate*a*a;
        wv[c] = w;
        rs[ii] += w;
        l0acc += 1.f/(1.f + expf(-(logA + 1.58261088f)));
      }
      ushort4 bw;
      bw.x = f2bf(wv[0]); bw.y = f2bf(wv[1]); bw.z = f2bf(wv[2]); bw.w = f2bf(wv[3]);
      *(ushort4*)(bwrow + jl) = bw;
      outrow[jl+0] = wv[0]; outrow[jl+1] = wv[1];   // out+17: 4B-aligned only
      outrow[jl+2] = wv[2]; outrow[jl+3] = wv[3];
    }
  }

  #pragma unroll
  for (int m = 1; m < 16; m <<= 1) {
    rs[0] += __shfl_xor(rs[0], m, 16);
    rs[1] += __shfl_xor(rs[1], m, 16);
  }
  if (jslot == 0) {
    atomicAdd(&row_sum[b*Nn + ia], rs[0]);
    atomicAdd(&row_sum[b*Nn + ib], rs[1]);
  }
  #pragma unroll
  for (int m = 1; m < 64; m <<= 1) l0acc += __shfl_xor(l0acc, m, 64);
  if ((t & 63) == 0) atomicAdd(l0_sum, l0acc);
}

// ---------------------------------------------------------------------------
// K3/K4: pipelined MFMA GEMM, 64x64 tile, 4 waves (2x2 of 32x32).
// A bf16 row-major [M][K]. OP0: B = bf16 k-packed granules, C = bf16 with
// 1/(rowsum+1e-8) row scale. OP1: B = f32 row-major (inline bf16 convert),
// C = f32 relu(x + bias).
// K-loop: VGPR prefetch of tile k+1 issued right after barrier; its waitcnt
// lands before next iter's LDS write, so loads drain under the MFMA section.
// As granules padded to stride 65 (2-way max staging conflict).
template<int OP>
__global__ __launch_bounds__(256) void mfma_gemm64(
    const ushort* __restrict__ A, const ushort* __restrict__ Bpk,
    const float* __restrict__ Bf32, int M, int N, int K,
    long sA, long sB, long sC, const float* __restrict__ aux,
    ushort* __restrict__ Cb, float* __restrict__ Cf)
{
  const int bb = blockIdx.z;
  const int m0 = blockIdx.y*64, n0 = blockIdx.x*64;
  const int t = threadIdx.x;
  const int lane = t & 63, l15 = lane & 15, quad = lane >> 4;
  const int wv = t >> 6, wr = wv & 1, wc = wv >> 1;

  __shared__ ushort As[(3*65 + 63 + 1)*8];   // granule (akq*65 + m)*8
  __shared__ ushort Bs[4*64*8];              // granule (bkq*64 + n)*8

  const ushort* Ab = A + (long)bb*sA;
  const int am = t >> 2, akq = t & 3;        // A: 16B/thread, global-coalesced
  const int bn = t & 63, bkq = t >> 6;       // B: contiguous granule rows

  f32x4 acc[2][2];
  #pragma unroll
  for (int i = 0; i < 2; ++i)
    #pragma unroll
    for (int j = 0; j < 2; ++j) acc[i][j] = (f32x4){0.f,0.f,0.f,0.f};

  uint4 ra = *(const uint4*)(Ab + (long)(m0+am)*K + akq*8);
  uint4 rbu;
  float rbf[8];
  if (OP == 0) {
    const ushort* Bb = Bpk + (long)bb*sB;
    rbu = *(const uint4*)(Bb + ((long)bkq*N + n0 + bn)*8);
  } else {
    #pragma unroll
    for (int j = 0; j < 8; ++j) rbf[j] = Bf32[(long)(bkq*8 + j)*N + n0 + bn];
  }

  for (int k0 = 0; k0 < K; k0 += 32) {
    *(uint4*)(As + (akq*65 + am)*8) = ra;
    if (OP == 0) {
      *(uint4*)(Bs + (bkq*64 + bn)*8) = rbu;
    } else {
      ushort tmp[8];
      #pragma unroll
      for (int j = 0; j < 8; ++j) tmp[j] = f2bf(rbf[j]);
      *(uint4*)(Bs + (bkq*64 + bn)*8) = *(uint4*)tmp;
    }
    __syncthreads();
    if (k0 + 32 < K) {
      ra = *(const uint4*)(Ab + (long)(m0+am)*K + (k0+32) + akq*8);
      if (OP == 0) {
        const ushort* Bb = Bpk + (long)bb*sB;
        rbu = *(const uint4*)(Bb + ((long)(((k0+32) >> 3) + bkq)*N + n0 + bn)*8);
      } else {
        #pragma unroll
        for (int j = 0; j < 8; ++j)
          rbf[j] = Bf32[(long)(k0 + 32 + bkq*8 + j)*N + n0 + bn];
      }
    }
    bf16x8 af[2], bfr[2];
    #pragma unroll
    for (int i = 0; i < 2; ++i)
      af[i] = *(const bf16x8*)(As + (quad*65 + wr*32 + i*16 + l15)*8);
    #pragma unroll
    for (int j = 0; j < 2; ++j)
      bfr[j] = *(const bf16x8*)(Bs + (quad*64 + wc*32 + j*16 + l15)*8);
    #pragma unroll
    for (int i = 0; i < 2; ++i)
      #pragma unroll
      for (int j = 0; j < 2; ++j)
        acc[i][j] = __builtin_amdgcn_mfma_f32_16x16x32_bf16(
            af[i], bfr[j], acc[i][j], 0, 0, 0);
    __syncthreads();
  }

  #pragma unroll
  for (int i = 0; i < 2; ++i) {
    #pragma unroll
    for (int j = 0; j < 2; ++j) {
      const int col = n0 + wc*32 + j*16 + l15;
      #pragma unroll
      for (int rr = 0; rr < 4; ++rr) {
        const int row = m0 + wr*32 + i*16 + quad*4 + rr;
        float v2 = acc[i][j][rr];
        if (OP == 0) {
          const float scl = 1.f/(aux[bb*M + row] + 1e-8f);
          Cb[(long)bb*sC + (long)row*N + col] = f2bf(v2*scl);
        } else {
          v2 += aux[col];
          Cf[(long)row*N + col] = fmaxf(v2, 0.f);
        }
      }
    }
  }
}

// ---------------------------------------------------------------------------
// K5: fused masked softmax (recomputed per block) + attention pooling.
// grid (8 chunks, 8 batches); chunk = 64 nodes; atomics into gr.
__global__ __launch_bounds__(256) void pool_fused(
    const float* __restrict__ row_sum, const float* __restrict__ masks,
    const float* __restrict__ h, float* __restrict__ gr)
{
  const int ic = blockIdx.x, b = blockIdx.y;
  const int t = threadIdx.x;
  __shared__ float red[256];
  __shared__ float attn_s[64];
  const float m0 = masks[b*Nn + t], m1 = masks[b*Nn + t + 256];
  const float l0v = (m0 > 0.f) ? row_sum[b*Nn + t] : -1e9f;
  const float l1v = (m1 > 0.f) ? row_sum[b*Nn + t + 256] : -1e9f;
  red[t] = fmaxf(l0v, l1v); __syncthreads();
  for (int s = 128; s > 0; s >>= 1) { if (t < s) red[t] = fmaxf(red[t], red[t+s]); __syncthreads(); }
  const float mx = red[0]; __syncthreads();
  const float ev0 = expf(l0v - mx), ev1 = expf(l1v - mx);
  red[t] = ev0 + ev1; __syncthreads();
  for (int s = 128; s > 0; s >>= 1) { if (t < s) red[t] += red[t+s]; __syncthreads(); }
  const float sinv = 1.f/red[0];
  __syncthreads();
  if (t < 64) {
    const int node = ic*64 + t;
    const float mm = masks[b*Nn + node];
    const float lv = (mm > 0.f) ? row_sum[b*Nn + node] : -1e9f;
    attn_s[t] = expf(lv - mx)*sinv;
  }
  __syncthreads();
  float acc = 0.f;
  #pragma unroll 4
  for (int i2 = 0; i2 < 64; ++i2)
    acc += attn_s[i2]*h[((long)(b*Nn + ic*64 + i2))*Hh + t];
  atomicAdd(&gr[b*Hh + t], acc);
}

// ---------------------------------------------------------------------------
// K6: classifier head + spectral norm + losses. Single block.
__global__ __launch_bounds__(256) void classifier_kernel(
    const float* __restrict__ gr, const float* __restrict__ W1c,
    const float* __restrict__ b1c, const float* __restrict__ ln_g,
    const float* __restrict__ ln_b, const float* __restrict__ W2c,
    const float* __restrict__ b2c, const float* __restrict__ u_sn,
    const int* __restrict__ labels, const float* __restrict__ l0_sum,
    float* __restrict__ out)
{
  const int t = threadIdx.x;
  __shared__ float grs[2048];
  __shared__ float z[8][128];
  __shared__ float red[256];
  __shared__ float vv[128];
  __shared__ float mu_s[8], ri_s[8];
  __shared__ float lg[16];
  for (int p = t; p < 2048; p += 256) grs[p] = gr[p];
  __syncthreads();
  #pragma unroll
  for (int p = 0; p < 4; ++p) {
    const int idx = t + p*256;
    const int b = idx >> 7, o = idx & 127;
    float acc = b1c[o];
    for (int d = 0; d < 256; ++d) acc += grs[b*256 + d]*W1c[d*128 + o];
    z[b][o] = fmaxf(acc, 0.f);
  }
  __syncthreads();
  if (t < 8) {
    float mu = 0.f;
    for (int o = 0; o < 128; ++o) mu += z[t][o];
    mu *= (1.f/128.f);
    float var = 0.f;
    for (int o = 0; o < 128; ++o) { const float d = z[t][o]-mu; var += d*d; }
    var *= (1.f/128.f);
    mu_s[t] = mu; ri_s[t] = rsqrtf(var + 1e-5f);
  }
  const float u0 = u_sn[0], u1 = u_sn[1];
  float vt = 0.f;
  if (t < 128) { vt = W2c[2*t]*u0 + W2c[2*t+1]*u1; vv[t] = vt; }
  red[t] = (t < 128) ? vt*vt : 0.f;
  __syncthreads();
  for (int s = 128; s > 0; s >>= 1) { if (t < s) red[t] += red[t+s]; __syncthreads(); }
  const float vninv = 1.f/fmaxf(sqrtf(red[0]), 1e-12f);
  __syncthreads();
  red[t] = (t < 128) ? W2c[2*t]*vv[t]*vninv : 0.f;
  __syncthreads();
  for (int s = 128; s > 0; s >>= 1) { if (t < s) red[t] += red[t+s]; __syncthreads(); }
  const float u20 = red[0];
  __syncthreads();
  red[t] = (t < 128) ? W2c[2*t+1]*vv[t]*vninv : 0.f;
  __syncthreads();
  for (int s = 128; s > 0; s >>= 1) { if (t < s) red[t] += red[t+s]; __syncthreads(); }
  const float u21 = red[0];
  __syncthreads();
  const float uninv = 1.f/fmaxf(sqrtf(u20*u20 + u21*u21), 1e-12f);
  const float u2n0 = u20*uninv, u2n1 = u21*uninv;
  red[t] = (t < 128) ? vv[t]*vninv*(W2c[2*t]*u2n0 + W2c[2*t+1]*u2n1) : 0.f;
  __syncthreads();
  for (int s = 128; s > 0; s >>= 1) { if (t < s) red[t] += red[t+s]; __syncthreads(); }
  const float sinv = 1.f/red[0];
  __syncthreads();
  if (t < 16) {
    const int b = t >> 1, c = t & 1;
    const float mu = mu_s[b], ri = ri_s[b];
    float acc = 0.f;
    for (int o = 0; o < 128; ++o) {
      const float zln = (z[b][o]-mu)*ri*ln_g[o] + ln_b[o];
      acc += zln*W2c[2*o + c];
    }
    const float lgv = acc*sinv + b2c[c];
    lg[t] = lgv;
    out[t] = lgv;
  }
  __syncthreads();
  if (t == 0) {
    float closs = 0.f;
    for (int b = 0; b < 8; ++b) {
      const float a0 = lg[2*b], a1 = lg[2*b+1];
      const float m = fmaxf(a0, a1);
      const float lse = m + logf(expf(a0-m) + expf(a1-m));
      closs += lse - lg[2*b + labels[b]];
    }
    closs *= (1.f/8.f);
    out[16] = closs + 0.01f*l0_sum[0];
  }
}

extern "C" void kernel_launch(void* const* d_in, const int* in_sizes, int n_in,
                              void* d_out, int out_size, void* d_ws, size_t ws_size,
                              hipStream_t stream) {
  const float* node_feat = (const float*)d_in[0];
  const int*   labels    = (const int*)d_in[1];
  const float* adjs      = (const float*)d_in[2];
  const float* masks     = (const float*)d_in[3];
  const float* Wa        = (const float*)d_in[4];
  const float* Wb        = (const float*)d_in[5];
  const float* be        = (const float*)d_in[6];
  const float* W2e       = (const float*)d_in[7];
  const float* b2e       = (const float*)d_in[8];
  const float* Wconv     = (const float*)d_in[9];
  const float* bconv     = (const float*)d_in[10];
  const float* W1c       = (const float*)d_in[11];
  const float* b1c       = (const float*)d_in[12];
  const float* ln_g      = (const float*)d_in[13];
  const float* ln_b      = (const float*)d_in[14];
  const float* W2c       = (const float*)d_in[15];
  const float* b2c       = (const float*)d_in[16];
  const float* u_sn      = (const float*)d_in[17];

  float* out = (float*)d_out;
  float* ws  = (float*)d_ws;
  ushort* nfpk   = (ushort*)(ws + WS_NFPK);
  float*  e1     = ws + WS_E1;
  float*  e2     = ws + WS_E2;
  ushort* wadjb  = (ushort*)(ws + WS_WADJB);
  float*  row_sum= ws + WS_RS;
  float*  l0s    = ws + WS_L0;
  ushort* haggb  = (ushort*)(ws + WS_HAGGB);
  float*  h      = ws + WS_H;
  float*  gr     = ws + WS_GR;

  norm_e12_fused<<<256, 256, 0, stream>>>(node_feat, Wa, Wb, be, nfpk, e1, e2,
                                          row_sum, gr, l0s);
  edge_kernel<<<dim3(Nn/128, Nn/32, Bsz), 256, 0, stream>>>(
      e1, e2, W2e, b2e, adjs, out + 17, wadjb, row_sum, l0s);
  // h_agg[b] = (wadj[b]/rowsum) @ nf[b]  (batched 512x512x512)
  mfma_gemm64<0><<<dim3(8, 8, 8), 256, 0, stream>>>(
      wadjb, nfpk, nullptr, 512, 512, 512, 262144L, 262144L, 262144L,
      row_sum, haggb, nullptr);
  // h = relu(h_agg @ Wconv + bconv)  (M=4096, N=256, K=512), Wconv f32 inline
  mfma_gemm64<1><<<dim3(4, 64, 1), 256, 0, stream>>>(
      haggb, nullptr, Wconv, 4096, 256, 512, 0, 0, 0,
      bconv, nullptr, h);
  pool_fused<<<dim3(8, Bsz), 256, 0, stream>>>(row_sum, masks, h, gr);
  classifier_kernel<<<1, 256, 0, stream>>>(gr, W1c, b1c, ln_g, ln_b, W2c, b2c,
                                           u_sn, labels, l0s, out);
}

// Round 5
// 199.920 us; speedup vs baseline: 1.5407x; 1.0094x over previous
//
#include <hip/hip_runtime.h>

// ---------------------------------------------------------------------------
// ImprovedEdgeGNN forward — MI355X
// Sizes: B=8, N=512, D=512, H=256, E=32, C=2
// out layout: [0:16) logits [8,2], [16] total_loss, [17:17+8*512*512) wadj
// R5: fix R4's workspace-overlap bug (wadjb/haggb were half-sized -> row_sum
//     clobber + gemm race). Algebraic refactor: h = (wadj/rs)@(nf@Wconv),
//     nfc fused into norm kernel (nf never hits global), pool fused into
//     gemm epilogue (h never hits global). 5 launches.
// ---------------------------------------------------------------------------

#define Bsz 8
#define Nn  512
#define Dd  512
#define Hh  256
#define Ee  32

// ws offsets (floats) — sizes audited this round:
#define WS_NFCPK  0L          // nfc bf16 k-packed [8][64oct][256c][8] = 1,048,576 us = 524,288 f
#define WS_E1     524288L     // [4096][32] f32 (be folded)            131,072 f
#define WS_E2     655360L     // [4096][32] f32                        131,072 f
#define WS_WADJB  786432L     // wadj bf16 [8][512][512] = 2,097,152 us = 1,048,576 f
#define WS_RS     1835008L    // [4096] raw row sums (= imp)           4,096 f
#define WS_L0     1839104L    // [8]
#define WS_GR     1839112L    // [8][256]                              2,048 f
#define WS_WABPK  1841160L    // [Wa|Wb] bf16 pk [64kq][64n][8] = 32,768 us = 16,384 f
#define WS_WCPK   1857544L    // Wconv bf16 pk [64kq][256n][8] = 131,072 us = 65,536 f

typedef __bf16 bf16x8 __attribute__((ext_vector_type(8)));
typedef float  f32x4  __attribute__((ext_vector_type(4)));

__device__ inline ushort f2bf(float f) {
  union { float f; unsigned u; } c; c.f = f;
  return (ushort)((c.u + 0x7fffu + ((c.u >> 16) & 1u)) >> 16);
}

// ---------------------------------------------------------------------------
// K0: pack weights to bf16 k-packed granules [(K/8)][N][8].
__global__ __launch_bounds__(256) void pack_weights(
    const float* __restrict__ Wconv, const float* __restrict__ Wa,
    const float* __restrict__ Wb, ushort* __restrict__ wcpk,
    ushort* __restrict__ wabpk)
{
  const int g = blockIdx.x*256 + threadIdx.x;
  if (g < 16384) {                       // Wconv granules
    const int kq = g >> 8, n = g & 255;
    ushort tmp[8];
    #pragma unroll
    for (int j = 0; j < 8; ++j) tmp[j] = f2bf(Wconv[(kq*8 + j)*Hh + n]);
    *(uint4*)(wcpk + (long)g*8) = *(uint4*)tmp;
  } else if (g < 16384 + 4096) {         // Wa|Wb granules
    const int gg = g - 16384;
    const int kq = gg >> 6, n = gg & 63;
    const float* W = (n < 32) ? Wa : Wb;
    const int e = n & 31;
    ushort tmp[8];
    #pragma unroll
    for (int j = 0; j < 8; ++j) tmp[j] = f2bf(W[(kq*8 + j)*Ee + e]);
    *(uint4*)(wabpk + (long)gg*8) = *(uint4*)tmp;
  }
}

// ---------------------------------------------------------------------------
// K1: fused normalize + e1|e2 + nfc = nf@Wconv. 256 blocks x 16 rows.
//  - rows L2-normalized in registers, bf16 granules -> LDS A-tile (stride 17)
//  - e1|e2 (64 cols) and nfc (256 cols) via MFMA, B staged from packed
//    weights with VGPR prefetch
//  - nfc written k-packed (granules over node dim) via LDS transpose; this
//    is gemm_pool's B operand. nf itself never goes to global.
//  - zeroes row_sum rows (this block), gr + l0 (block 0)
__global__ __launch_bounds__(256) void norm_e12_nfc(
    const float* __restrict__ nfeat, const ushort* __restrict__ wabpk,
    const ushort* __restrict__ wcpk, const float* __restrict__ be,
    ushort* __restrict__ nfcpk, float* __restrict__ e1, float* __restrict__ e2,
    float* __restrict__ row_sum, float* __restrict__ gr,
    float* __restrict__ l0_sum)
{
  const int blk = blockIdx.x;
  const int r0 = blk*16;               // global row base (b*512 + local)
  const int b = r0 >> 9;
  const int t = threadIdx.x;
  const int r = t >> 4;                // local row 0..15
  const int seg = t & 15;              // 32-col segment

  __shared__ ushort As[(63*17 + 15 + 1)*8];   // granule (kq*17 + row)*8
  __shared__ ushort BsA[4*64*8];              // Wa|Wb tile granules
  __shared__ ushort BsC[4*256*8];             // Wconv tile granules (reused as nfc transpose tile)

  // ---- phase 1: load 32 f32/thread, row norm, bf16 granules to LDS ----
  float4 v[8];
  const float* src = nfeat + (long)(r0 + r)*Dd + seg*32;
  #pragma unroll
  for (int i = 0; i < 8; ++i) v[i] = *(const float4*)(src + i*4);
  float s = 0.f;
  #pragma unroll
  for (int i = 0; i < 8; ++i)
    s += v[i].x*v[i].x + v[i].y*v[i].y + v[i].z*v[i].z + v[i].w*v[i].w;
  #pragma unroll
  for (int m = 1; m < 16; m <<= 1) s += __shfl_xor(s, m, 16);
  const float sc = 1.f / fmaxf(sqrtf(s), 1e-12f);
  #pragma unroll
  for (int q = 0; q < 4; ++q) {
    ushort tmp[8];
    const float4 a = v[2*q], bq = v[2*q+1];
    tmp[0]=f2bf(a.x*sc);  tmp[1]=f2bf(a.y*sc);  tmp[2]=f2bf(a.z*sc);  tmp[3]=f2bf(a.w*sc);
    tmp[4]=f2bf(bq.x*sc); tmp[5]=f2bf(bq.y*sc); tmp[6]=f2bf(bq.z*sc); tmp[7]=f2bf(bq.w*sc);
    *(uint4*)(As + ((seg*4 + q)*17 + r)*8) = *(uint4*)tmp;
  }
  if (t < 16) row_sum[r0 + t] = 0.f;
  if (blk == 0) {
    for (int p = t; p < Bsz*Hh; p += 256) gr[p] = 0.f;
    if (t == 0) *l0_sum = 0.f;
  }

  // ---- phase 2: MFMA over K with prefetched packed-weight staging ----
  const int lane = t & 63, l15 = lane & 15, quad = lane >> 4;
  const int w = t >> 6;                  // wave id 0..3
  const int abq = t >> 6, abn = t & 63;  // Wa|Wb staging map

  f32x4 acc_e = {0.f, 0.f, 0.f, 0.f};
  f32x4 acc_c[4];
  #pragma unroll
  for (int j = 0; j < 4; ++j) acc_c[j] = (f32x4){0.f,0.f,0.f,0.f};

  uint4 pab = *(const uint4*)(wabpk + ((long)abq*64 + abn)*8);
  uint4 pc[4];
  #pragma unroll
  for (int p = 0; p < 4; ++p) {
    const int g = t + p*256;
    pc[p] = *(const uint4*)(wcpk + ((long)(g >> 8)*256 + (g & 255))*8);
  }
  __syncthreads();   // As ready; (first iter: BsA/BsC not yet read)

  for (int k0 = 0; k0 < 512; k0 += 32) {
    if (k0 > 0) __syncthreads();         // prior frag reads done
    *(uint4*)(BsA + (abq*64 + abn)*8) = pab;
    #pragma unroll
    for (int p = 0; p < 4; ++p) {
      const int g = t + p*256;
      *(uint4*)(BsC + ((g >> 8)*256 + (g & 255))*8) = pc[p];
    }
    __syncthreads();
    if (k0 + 32 < 512) {
      const int kb = (k0 + 32) >> 3;
      pab = *(const uint4*)(wabpk + ((long)(kb + abq)*64 + abn)*8);
      #pragma unroll
      for (int p = 0; p < 4; ++p) {
        const int g = t + p*256;
        pc[p] = *(const uint4*)(wcpk + ((long)(kb + (g >> 8))*256 + (g & 255))*8);
      }
    }
    const bf16x8 af = *(const bf16x8*)(As + (((k0 >> 3) + quad)*17 + l15)*8);
    const bf16x8 bfa = *(const bf16x8*)(BsA + (quad*64 + w*16 + l15)*8);
    acc_e = __builtin_amdgcn_mfma_f32_16x16x32_bf16(af, bfa, acc_e, 0, 0, 0);
    #pragma unroll
    for (int fn = 0; fn < 4; ++fn) {
      const bf16x8 bfc = *(const bf16x8*)(BsC + (quad*256 + w*64 + fn*16 + l15)*8);
      acc_c[fn] = __builtin_amdgcn_mfma_f32_16x16x32_bf16(af, bfc, acc_c[fn], 0, 0, 0);
    }
  }

  // ---- epilogue A: e1|e2 (wave w -> cols w*16..+15) ----
  {
    const int col = w*16 + l15;
    #pragma unroll
    for (int rr = 0; rr < 4; ++rr) {
      const int row = r0 + quad*4 + rr;
      if (col < 32) e1[(long)row*Ee + col] = acc_e[rr] + be[col];
      else          e2[(long)row*Ee + (col - 32)] = acc_e[rr];
    }
  }

  // ---- epilogue B: nfc -> k-packed global via LDS transpose ----
  __syncthreads();                       // all frag reads of BsC done
  ushort* tile = BsC;                    // [16][260] bf16
  #pragma unroll
  for (int fn = 0; fn < 4; ++fn) {
    const int col = w*64 + fn*16 + l15;
    #pragma unroll
    for (int rr = 0; rr < 4; ++rr)
      tile[(quad*4 + rr)*260 + col] = f2bf(acc_c[fn][rr]);
  }
  __syncthreads();
  #pragma unroll
  for (int p = 0; p < 2; ++p) {
    const int g = t + p*256;
    const int oct = g >> 8, c = g & 255;
    ushort tmp[8];
    #pragma unroll
    for (int j = 0; j < 8; ++j) tmp[j] = tile[(oct*8 + j)*260 + c];
    const long og = ((r0 & 511) >> 3) + oct;     // node-octet within batch
    *(uint4*)(nfcpk + ((long)b*16384 + og*256 + c)*8) = *(uint4*)tmp;
  }
}

// ---------------------------------------------------------------------------
// K2: tiled edge scoring. Block = (b, 32-row i-tile, 128-col j-tile).
__global__ __launch_bounds__(256) void edge_kernel(
    const float* __restrict__ e1, const float* __restrict__ e2,
    const float* __restrict__ W2e, const float* __restrict__ b2e,
    const float* __restrict__ adjs, float* __restrict__ out_wadj,
    ushort* __restrict__ wadj_b, float* __restrict__ row_sum,
    float* __restrict__ l0_sum)
{
  const int b  = blockIdx.z;
  const int i0 = blockIdx.y * 32;
  const int j0 = blockIdx.x * 128;
  const int t  = threadIdx.x;

  __shared__ float e2s[32*132];

  #pragma unroll
  for (int itr = 0; itr < 4; ++itr) {
    const int idx = t + itr*256;
    const int kq = idx & 7, jg = idx >> 3;
    const float4 v = *(const float4*)(e2 + ((long)(b*Nn + j0 + jg))*Ee + kq*4);
    e2s[(kq*4+0)*132 + jg] = v.x;
    e2s[(kq*4+1)*132 + jg] = v.y;
    e2s[(kq*4+2)*132 + jg] = v.z;
    e2s[(kq*4+3)*132 + jg] = v.w;
  }

  const int pair  = t >> 4;
  const int jslot = t & 15;
  const int ia = i0 + pair*2;
  const int ib = ia + 1;
  const int ja = jslot*4;
  const int jb = ja + 64;

  float e1af[32], e1bf[32], w2f[32];
  #pragma unroll
  for (int q = 0; q < 8; ++q) {
    *(float4*)(&e1af[q*4]) = *(const float4*)(e1 + ((long)(b*Nn + ia))*Ee + q*4);
    *(float4*)(&e1bf[q*4]) = *(const float4*)(e1 + ((long)(b*Nn + ib))*Ee + q*4);
    *(float4*)(&w2f[q*4])  = *(const float4*)(W2e + q*4);
  }
  const float b2 = b2e[0];
  __syncthreads();

  float acc[2][8] = {};
  #pragma unroll
  for (int k = 0; k < 32; ++k) {
    const float4 va = *(const float4*)(e2s + k*132 + ja);
    const float4 vb = *(const float4*)(e2s + k*132 + jb);
    const float w = w2f[k];
    const float ea = e1af[k], eb = e1bf[k];
    acc[0][0] += fmaxf(ea+va.x, 0.f)*w;
    acc[0][1] += fmaxf(ea+va.y, 0.f)*w;
    acc[0][2] += fmaxf(ea+va.z, 0.f)*w;
    acc[0][3] += fmaxf(ea+va.w, 0.f)*w;
    acc[0][4] += fmaxf(ea+vb.x, 0.f)*w;
    acc[0][5] += fmaxf(ea+vb.y, 0.f)*w;
    acc[0][6] += fmaxf(ea+vb.z, 0.f)*w;
    acc[0][7] += fmaxf(ea+vb.w, 0.f)*w;
    acc[1][0] += fmaxf(eb+va.x, 0.f)*w;
    acc[1][1] += fmaxf(eb+va.y, 0.f)*w;
    acc[1][2] += fmaxf(eb+va.z, 0.f)*w;
    acc[1][3] += fmaxf(eb+va.w, 0.f)*w;
    acc[1][4] += fmaxf(eb+vb.x, 0.f)*w;
    acc[1][5] += fmaxf(eb+vb.y, 0.f)*w;
    acc[1][6] += fmaxf(eb+vb.z, 0.f)*w;
    acc[1][7] += fmaxf(eb+vb.w, 0.f)*w;
  }

  float rs[2] = {0.f, 0.f};
  float l0acc = 0.f;
  #pragma unroll
  for (int ii = 0; ii < 2; ++ii) {
    const int i = (ii == 0) ? ia : ib;
    const float* arow = adjs     + ((long)(b*Nn + i))*Nn + j0;
    ushort* bwrow     = wadj_b   + ((long)(b*Nn + i))*Nn + j0;
    float* outrow     = out_wadj + ((long)(b*Nn + i))*Nn + j0;
    #pragma unroll
    for (int h2 = 0; h2 < 2; ++h2) {
      const int jl = (h2 == 0) ? ja : jb;
      const float4 av = *(const float4*)(arow + jl);
      float wv[4];
      #pragma unroll
      for (int c = 0; c < 4; ++c) {
        const float logA = acc[ii][h2*4 + c] + b2;
        const float sg = 1.f/(1.f + expf(-logA));
        const float gate = fminf(fmaxf(sg*1.2f - 0.1f, 0.f), 1.f);
        const float a = (c==0)?av.x:(c==1)?av.y:(c==2)?av.z:av.w;
        const float w = gate*a*a;
        wv[c] = w;
        rs[ii] += w;
        l0acc += 1.f/(1.f + expf(-(logA + 1.58261088f)));
      }
      ushort4 bw;
      bw.x = f2bf(wv[0]); bw.y = f2bf(wv[1]); bw.z = f2bf(wv[2]); bw.w = f2bf(wv[3]);
      *(ushort4*)(bwrow + jl) = bw;
      outrow[jl+0] = wv[0]; outrow[jl+1] = wv[1];   // out+17: 4B-aligned only
      outrow[jl+2] = wv[2]; outrow[jl+3] = wv[3];
    }
  }

  #pragma unroll
  for (int m = 1; m < 16; m <<= 1) {
    rs[0] += __shfl_xor(rs[0], m, 16);
    rs[1] += __shfl_xor(rs[1], m, 16);
  }
  if (jslot == 0) {
    atomicAdd(&row_sum[b*Nn + ia], rs[0]);
    atomicAdd(&row_sum[b*Nn + ib], rs[1]);
  }
  #pragma unroll
  for (int m = 1; m < 64; m <<= 1) l0acc += __shfl_xor(l0acc, m, 64);
  if ((t & 63) == 0) atomicAdd(l0_sum, l0acc);
}

// ---------------------------------------------------------------------------
// K3: gemm_pool. h_tile = relu((wadj/rs)@nfc + bconv), then attention-pool
// the tile directly into gr (h never hits global). 64x64 tile, 4 waves,
// VGPR-prefetched K-loop. Grid (N/64=4, M/64=8, B=8).
__global__ __launch_bounds__(256) void gemm_pool(
    const ushort* __restrict__ wadjb, const ushort* __restrict__ nfcpk,
    const float* __restrict__ row_sum, const float* __restrict__ masks,
    const float* __restrict__ bconv, float* __restrict__ gr)
{
  const int bb = blockIdx.z;
  const int m0 = blockIdx.y*64, n0 = blockIdx.x*64;
  const int t = threadIdx.x;
  const int lane = t & 63, l15 = lane & 15, quad = lane >> 4;
  const int wv = t >> 6, wr = wv & 1, wc = wv >> 1;

  __shared__ ushort As[(3*65 + 63 + 1)*8];   // granule (akq*65 + m)*8
  __shared__ ushort Bs[4*64*8];              // granule (bkq*64 + n)*8
  __shared__ float ptile[64*65];             // weighted h tile
  __shared__ float red[256];
  __shared__ float attn_s[64];
  __shared__ float mx_s, sinv_s;

  const ushort* Ab = wadjb + (long)bb*262144;
  const ushort* Bb = nfcpk + (long)bb*131072;
  const int am = t >> 2, akq = t & 3;
  const int bn = t & 63, bkq = t >> 6;

  f32x4 acc[2][2];
  #pragma unroll
  for (int i = 0; i < 2; ++i)
    #pragma unroll
    for (int j = 0; j < 2; ++j) acc[i][j] = (f32x4){0.f,0.f,0.f,0.f};

  uint4 ra = *(const uint4*)(Ab + (long)(m0+am)*512 + akq*8);
  uint4 rb = *(const uint4*)(Bb + ((long)bkq*256 + n0 + bn)*8);

  for (int k0 = 0; k0 < 512; k0 += 32) {
    if (k0 > 0) __syncthreads();
    *(uint4*)(As + (akq*65 + am)*8) = ra;
    *(uint4*)(Bs + (bkq*64 + bn)*8) = rb;
    __syncthreads();
    if (k0 + 32 < 512) {
      ra = *(const uint4*)(Ab + (long)(m0+am)*512 + (k0+32) + akq*8);
      rb = *(const uint4*)(Bb + ((long)(((k0+32) >> 3) + bkq)*256 + n0 + bn)*8);
    }
    bf16x8 af[2], bfr[2];
    #pragma unroll
    for (int i = 0; i < 2; ++i)
      af[i] = *(const bf16x8*)(As + (quad*65 + wr*32 + i*16 + l15)*8);
    #pragma unroll
    for (int j = 0; j < 2; ++j)
      bfr[j] = *(const bf16x8*)(Bs + (quad*64 + wc*32 + j*16 + l15)*8);
    #pragma unroll
    for (int i = 0; i < 2; ++i)
      #pragma unroll
      for (int j = 0; j < 2; ++j)
        acc[i][j] = __builtin_amdgcn_mfma_f32_16x16x32_bf16(
            af[i], bfr[j], acc[i][j], 0, 0, 0);
  }
  __syncthreads();

  // attention softmax over this batch's masked degrees (block-redundant)
  {
    const float mk0 = masks[bb*Nn + t], mk1 = masks[bb*Nn + t + 256];
    const float lv0 = (mk0 > 0.f) ? row_sum[bb*Nn + t] : -1e9f;
    const float lv1 = (mk1 > 0.f) ? row_sum[bb*Nn + t + 256] : -1e9f;
    red[t] = fmaxf(lv0, lv1); __syncthreads();
    for (int s = 128; s > 0; s >>= 1) { if (t < s) red[t] = fmaxf(red[t], red[t+s]); __syncthreads(); }
    if (t == 0) mx_s = red[0];
    __syncthreads();
    const float mx = mx_s;
    red[t] = expf(lv0 - mx) + expf(lv1 - mx); __syncthreads();
    for (int s = 128; s > 0; s >>= 1) { if (t < s) red[t] += red[t+s]; __syncthreads(); }
    if (t == 0) sinv_s = 1.f/red[0];
    __syncthreads();
    if (t < 64) {
      const int node = m0 + t;
      const float mm = masks[bb*Nn + node];
      const float lv = (mm > 0.f) ? row_sum[bb*Nn + node] : -1e9f;
      attn_s[t] = expf(lv - mx)*sinv_s;
    }
    __syncthreads();
  }

  // epilogue: h = relu(acc/rs + bias), weight by attn, stash in LDS
  #pragma unroll
  for (int i = 0; i < 2; ++i) {
    #pragma unroll
    for (int j = 0; j < 2; ++j) {
      const int lcol = wc*32 + j*16 + l15;
      const float bias = bconv[n0 + lcol];
      #pragma unroll
      for (int rr = 0; rr < 4; ++rr) {
        const int lrow = wr*32 + i*16 + quad*4 + rr;
        const int row = m0 + lrow;
        const float scl = 1.f/(row_sum[bb*Nn + row] + 1e-8f);
        const float hv = fmaxf(acc[i][j][rr]*scl + bias, 0.f);
        ptile[lrow*65 + lcol] = hv * attn_s[lrow];
      }
    }
  }
  __syncthreads();
  if (t < 64) {
    float s = 0.f;
    #pragma unroll 4
    for (int rr = 0; rr < 64; ++rr) s += ptile[rr*65 + t];
    atomicAdd(&gr[bb*Hh + n0 + t], s);
  }
}

// ---------------------------------------------------------------------------
// K4: classifier head + spectral norm + losses. Single block.
__global__ __launch_bounds__(256) void classifier_kernel(
    const float* __restrict__ gr, const float* __restrict__ W1c,
    const float* __restrict__ b1c, const float* __restrict__ ln_g,
    const float* __restrict__ ln_b, const float* __restrict__ W2c,
    const float* __restrict__ b2c, const float* __restrict__ u_sn,
    const int* __restrict__ labels, const float* __restrict__ l0_sum,
    float* __restrict__ out)
{
  const int t = threadIdx.x;
  __shared__ float grs[2048];
  __shared__ float z[8][128];
  __shared__ float red[256];
  __shared__ float vv[128];
  __shared__ float mu_s[8], ri_s[8];
  __shared__ float lg[16];
  for (int p = t; p < 2048; p += 256) grs[p] = gr[p];
  __syncthreads();
  #pragma unroll
  for (int p = 0; p < 4; ++p) {
    const int idx = t + p*256;
    const int b = idx >> 7, o = idx & 127;
    float acc = b1c[o];
    for (int d = 0; d < 256; ++d) acc += grs[b*256 + d]*W1c[d*128 + o];
    z[b][o] = fmaxf(acc, 0.f);
  }
  __syncthreads();
  if (t < 8) {
    float mu = 0.f;
    for (int o = 0; o < 128; ++o) mu += z[t][o];
    mu *= (1.f/128.f);
    float var = 0.f;
    for (int o = 0; o < 128; ++o) { const float d = z[t][o]-mu; var += d*d; }
    var *= (1.f/128.f);
    mu_s[t] = mu; ri_s[t] = rsqrtf(var + 1e-5f);
  }
  const float u0 = u_sn[0], u1 = u_sn[1];
  float vt = 0.f;
  if (t < 128) { vt = W2c[2*t]*u0 + W2c[2*t+1]*u1; vv[t] = vt; }
  red[t] = (t < 128) ? vt*vt : 0.f;
  __syncthreads();
  for (int s = 128; s > 0; s >>= 1) { if (t < s) red[t] += red[t+s]; __syncthreads(); }
  const float vninv = 1.f/fmaxf(sqrtf(red[0]), 1e-12f);
  __syncthreads();
  red[t] = (t < 128) ? W2c[2*t]*vv[t]*vninv : 0.f;
  __syncthreads();
  for (int s = 128; s > 0; s >>= 1) { if (t < s) red[t] += red[t+s]; __syncthreads(); }
  const float u20 = red[0];
  __syncthreads();
  red[t] = (t < 128) ? W2c[2*t+1]*vv[t]*vninv : 0.f;
  __syncthreads();
  for (int s = 128; s > 0; s >>= 1) { if (t < s) red[t] += red[t+s]; __syncthreads(); }
  const float u21 = red[0];
  __syncthreads();
  const float uninv = 1.f/fmaxf(sqrtf(u20*u20 + u21*u21), 1e-12f);
  const float u2n0 = u20*uninv, u2n1 = u21*uninv;
  red[t] = (t < 128) ? vv[t]*vninv*(W2c[2*t]*u2n0 + W2c[2*t+1]*u2n1) : 0.f;
  __syncthreads();
  for (int s = 128; s > 0; s >>= 1) { if (t < s) red[t] += red[t+s]; __syncthreads(); }
  const float sinv = 1.f/red[0];
  __syncthreads();
  if (t < 16) {
    const int b = t >> 1, c = t & 1;
    const float mu = mu_s[b], ri = ri_s[b];
    float acc = 0.f;
    for (int o = 0; o < 128; ++o) {
      const float zln = (z[b][o]-mu)*ri*ln_g[o] + ln_b[o];
      acc += zln*W2c[2*o + c];
    }
    const float lgv = acc*sinv + b2c[c];
    lg[t] = lgv;
    out[t] = lgv;
  }
  __syncthreads();
  if (t == 0) {
    float closs = 0.f;
    for (int b = 0; b < 8; ++b) {
      const float a0 = lg[2*b], a1 = lg[2*b+1];
      const float m = fmaxf(a0, a1);
      const float lse = m + logf(expf(a0-m) + expf(a1-m));
      closs += lse - lg[2*b + labels[b]];
    }
    closs *= (1.f/8.f);
    out[16] = closs + 0.01f*l0_sum[0];
  }
}

extern "C" void kernel_launch(void* const* d_in, const int* in_sizes, int n_in,
                              void* d_out, int out_size, void* d_ws, size_t ws_size,
                              hipStream_t stream) {
  const float* node_feat = (const float*)d_in[0];
  const int*   labels    = (const int*)d_in[1];
  const float* adjs      = (const float*)d_in[2];
  const float* masks     = (const float*)d_in[3];
  const float* Wa        = (const float*)d_in[4];
  const float* Wb        = (const float*)d_in[5];
  const float* be        = (const float*)d_in[6];
  const float* W2e       = (const float*)d_in[7];
  const float* b2e       = (const float*)d_in[8];
  const float* Wconv     = (const float*)d_in[9];
  const float* bconv     = (const float*)d_in[10];
  const float* W1c       = (const float*)d_in[11];
  const float* b1c       = (const float*)d_in[12];
  const float* ln_g      = (const float*)d_in[13];
  const float* ln_b      = (const float*)d_in[14];
  const float* W2c       = (const float*)d_in[15];
  const float* b2c       = (const float*)d_in[16];
  const float* u_sn      = (const float*)d_in[17];

  float* out = (float*)d_out;
  float* ws  = (float*)d_ws;
  ushort* nfcpk  = (ushort*)(ws + WS_NFCPK);
  float*  e1     = ws + WS_E1;
  float*  e2     = ws + WS_E2;
  ushort* wadjb  = (ushort*)(ws + WS_WADJB);
  float*  row_sum= ws + WS_RS;
  float*  l0s    = ws + WS_L0;
  float*  gr     = ws + WS_GR;
  ushort* wabpk  = (ushort*)(ws + WS_WABPK);
  ushort* wcpk   = (ushort*)(ws + WS_WCPK);

  pack_weights<<<80, 256, 0, stream>>>(Wconv, Wa, Wb, wcpk, wabpk);
  norm_e12_nfc<<<256, 256, 0, stream>>>(node_feat, wabpk, wcpk, be, nfcpk,
                                        e1, e2, row_sum, gr, l0s);
  edge_kernel<<<dim3(Nn/128, Nn/32, Bsz), 256, 0, stream>>>(
      e1, e2, W2e, b2e, adjs, out + 17, wadjb, row_sum, l0s);
  gemm_pool<<<dim3(Hh/64, Nn/64, Bsz), 256, 0, stream>>>(
      wadjb, nfcpk, row_sum, masks, bconv, gr);
  classifier_kernel<<<1, 256, 0, stream>>>(gr, W1c, b1c, ln_g, ln_b, W2c, b2c,
                                           u_sn, labels, l0s, out);
}

// Round 6
// 198.682 us; speedup vs baseline: 1.5503x; 1.0062x over previous
//
#include <hip/hip_runtime.h>

// ---------------------------------------------------------------------------
// ImprovedEdgeGNN forward — MI355X
// Sizes: B=8, N=512, D=512, H=256, E=32, C=2
// out layout: [0:16) logits [8,2], [16] total_loss, [17:17+8*512*512) wadj
// R6: double-buffered K-loops in norm_e12_nfc and gemm_pool (1 barrier/iter,
//     was 2). Floor probe: kernels estimated ~30us of the 200us dur; if this
//     round moves <1.5%, dur is harness reset overhead (268MB ws poison).
// ---------------------------------------------------------------------------

#define Bsz 8
#define Nn  512
#define Dd  512
#define Hh  256
#define Ee  32

// ws offsets (floats)
#define WS_NFCPK  0L          // nfc bf16 k-packed [8][64oct][256c][8] = 524,288 f
#define WS_E1     524288L     // [4096][32] f32 (be folded)            131,072 f
#define WS_E2     655360L     // [4096][32] f32                        131,072 f
#define WS_WADJB  786432L     // wadj bf16 [8][512][512]             1,048,576 f
#define WS_RS     1835008L    // [4096] raw row sums (= imp)
#define WS_L0     1839104L    // [8]
#define WS_GR     1839112L    // [8][256]
#define WS_WABPK  1841160L    // [Wa|Wb] bf16 pk [64kq][64n][8]         16,384 f
#define WS_WCPK   1857544L    // Wconv bf16 pk [64kq][256n][8]          65,536 f

typedef __bf16 bf16x8 __attribute__((ext_vector_type(8)));
typedef float  f32x4  __attribute__((ext_vector_type(4)));

__device__ inline ushort f2bf(float f) {
  union { float f; unsigned u; } c; c.f = f;
  return (ushort)((c.u + 0x7fffu + ((c.u >> 16) & 1u)) >> 16);
}

// ---------------------------------------------------------------------------
// K0: pack weights to bf16 k-packed granules [(K/8)][N][8].
__global__ __launch_bounds__(256) void pack_weights(
    const float* __restrict__ Wconv, const float* __restrict__ Wa,
    const float* __restrict__ Wb, ushort* __restrict__ wcpk,
    ushort* __restrict__ wabpk)
{
  const int g = blockIdx.x*256 + threadIdx.x;
  if (g < 16384) {                       // Wconv granules
    const int kq = g >> 8, n = g & 255;
    ushort tmp[8];
    #pragma unroll
    for (int j = 0; j < 8; ++j) tmp[j] = f2bf(Wconv[(kq*8 + j)*Hh + n]);
    *(uint4*)(wcpk + (long)g*8) = *(uint4*)tmp;
  } else if (g < 16384 + 4096) {         // Wa|Wb granules
    const int gg = g - 16384;
    const int kq = gg >> 6, n = gg & 63;
    const float* W = (n < 32) ? Wa : Wb;
    const int e = n & 31;
    ushort tmp[8];
    #pragma unroll
    for (int j = 0; j < 8; ++j) tmp[j] = f2bf(W[(kq*8 + j)*Ee + e]);
    *(uint4*)(wabpk + (long)gg*8) = *(uint4*)tmp;
  }
}

// ---------------------------------------------------------------------------
// K1: fused normalize + e1|e2 + nfc = nf@Wconv. 256 blocks x 16 rows.
// Double-buffered B staging: one barrier per K-iter.
__global__ __launch_bounds__(256) void norm_e12_nfc(
    const float* __restrict__ nfeat, const ushort* __restrict__ wabpk,
    const ushort* __restrict__ wcpk, const float* __restrict__ be,
    ushort* __restrict__ nfcpk, float* __restrict__ e1, float* __restrict__ e2,
    float* __restrict__ row_sum, float* __restrict__ gr,
    float* __restrict__ l0_sum)
{
  const int blk = blockIdx.x;
  const int r0 = blk*16;               // global row base (b*512 + local)
  const int b = r0 >> 9;
  const int t = threadIdx.x;
  const int r = t >> 4;                // local row 0..15
  const int seg = t & 15;              // 32-col segment

  __shared__ ushort As[(63*17 + 15 + 1)*8];   // granule (kq*17 + row)*8
  __shared__ ushort BsA[2][4*64*8];           // Wa|Wb tile granules (dbuf)
  __shared__ ushort BsC[2][4*256*8];          // Wconv tile granules (dbuf)

  // ---- phase 1: load 32 f32/thread, row norm, bf16 granules to LDS ----
  float4 v[8];
  const float* src = nfeat + (long)(r0 + r)*Dd + seg*32;
  #pragma unroll
  for (int i = 0; i < 8; ++i) v[i] = *(const float4*)(src + i*4);
  float s = 0.f;
  #pragma unroll
  for (int i = 0; i < 8; ++i)
    s += v[i].x*v[i].x + v[i].y*v[i].y + v[i].z*v[i].z + v[i].w*v[i].w;
  #pragma unroll
  for (int m = 1; m < 16; m <<= 1) s += __shfl_xor(s, m, 16);
  const float sc = 1.f / fmaxf(sqrtf(s), 1e-12f);
  #pragma unroll
  for (int q = 0; q < 4; ++q) {
    ushort tmp[8];
    const float4 a = v[2*q], bq = v[2*q+1];
    tmp[0]=f2bf(a.x*sc);  tmp[1]=f2bf(a.y*sc);  tmp[2]=f2bf(a.z*sc);  tmp[3]=f2bf(a.w*sc);
    tmp[4]=f2bf(bq.x*sc); tmp[5]=f2bf(bq.y*sc); tmp[6]=f2bf(bq.z*sc); tmp[7]=f2bf(bq.w*sc);
    *(uint4*)(As + ((seg*4 + q)*17 + r)*8) = *(uint4*)tmp;
  }
  if (t < 16) row_sum[r0 + t] = 0.f;
  if (blk == 0) {
    for (int p = t; p < Bsz*Hh; p += 256) gr[p] = 0.f;
    if (t == 0) *l0_sum = 0.f;
  }

  // ---- phase 2: MFMA over K, double-buffered weight staging ----
  const int lane = t & 63, l15 = lane & 15, quad = lane >> 4;
  const int w = t >> 6;                  // wave id 0..3
  const int abq = t >> 6, abn = t & 63;  // Wa|Wb staging map

  f32x4 acc_e = {0.f, 0.f, 0.f, 0.f};
  f32x4 acc_c[4];
  #pragma unroll
  for (int j = 0; j < 4; ++j) acc_c[j] = (f32x4){0.f,0.f,0.f,0.f};

  // stage k=0 into buf 0, then prefetch k=32 into regs
  uint4 pab = *(const uint4*)(wabpk + ((long)abq*64 + abn)*8);
  uint4 pc[4];
  #pragma unroll
  for (int p = 0; p < 4; ++p) {
    const int g = t + p*256;
    pc[p] = *(const uint4*)(wcpk + ((long)(g >> 8)*256 + (g & 255))*8);
  }
  *(uint4*)(BsA[0] + (abq*64 + abn)*8) = pab;
  #pragma unroll
  for (int p = 0; p < 4; ++p) {
    const int g = t + p*256;
    *(uint4*)(BsC[0] + ((g >> 8)*256 + (g & 255))*8) = pc[p];
  }
  {
    pab = *(const uint4*)(wabpk + ((long)(4 + abq)*64 + abn)*8);
    #pragma unroll
    for (int p = 0; p < 4; ++p) {
      const int g = t + p*256;
      pc[p] = *(const uint4*)(wcpk + ((long)(4 + (g >> 8))*256 + (g & 255))*8);
    }
  }

  for (int k0 = 0; k0 < 512; k0 += 32) {
    const int pb = (k0 >> 5) & 1;
    __syncthreads();                     // buf[pb] writes visible; old reads done
    if (k0 + 32 < 512) {
      // stage k0+32 into buf[1-pb] (regs hold it), then prefetch k0+64
      *(uint4*)(BsA[1-pb] + (abq*64 + abn)*8) = pab;
      #pragma unroll
      for (int p = 0; p < 4; ++p) {
        const int g = t + p*256;
        *(uint4*)(BsC[1-pb] + ((g >> 8)*256 + (g & 255))*8) = pc[p];
      }
      if (k0 + 64 < 512) {
        const int kb = (k0 + 64) >> 3;
        pab = *(const uint4*)(wabpk + ((long)(kb + abq)*64 + abn)*8);
        #pragma unroll
        for (int p = 0; p < 4; ++p) {
          const int g = t + p*256;
          pc[p] = *(const uint4*)(wcpk + ((long)(kb + (g >> 8))*256 + (g & 255))*8);
        }
      }
    }
    const bf16x8 af = *(const bf16x8*)(As + (((k0 >> 3) + quad)*17 + l15)*8);
    const bf16x8 bfa = *(const bf16x8*)(BsA[pb] + (quad*64 + w*16 + l15)*8);
    acc_e = __builtin_amdgcn_mfma_f32_16x16x32_bf16(af, bfa, acc_e, 0, 0, 0);
    #pragma unroll
    for (int fn = 0; fn < 4; ++fn) {
      const bf16x8 bfc = *(const bf16x8*)(BsC[pb] + (quad*256 + w*64 + fn*16 + l15)*8);
      acc_c[fn] = __builtin_amdgcn_mfma_f32_16x16x32_bf16(af, bfc, acc_c[fn], 0, 0, 0);
    }
  }

  // ---- epilogue A: e1|e2 (wave w -> cols w*16..+15) ----
  {
    const int col = w*16 + l15;
    #pragma unroll
    for (int rr = 0; rr < 4; ++rr) {
      const int row = r0 + quad*4 + rr;
      if (col < 32) e1[(long)row*Ee + col] = acc_e[rr] + be[col];
      else          e2[(long)row*Ee + (col - 32)] = acc_e[rr];
    }
  }

  // ---- epilogue B: nfc -> k-packed global via LDS transpose ----
  __syncthreads();                       // all frag reads of BsC done
  ushort* tile = BsC[0];                 // [16][260] bf16
  #pragma unroll
  for (int fn = 0; fn < 4; ++fn) {
    const int col = w*64 + fn*16 + l15;
    #pragma unroll
    for (int rr = 0; rr < 4; ++rr)
      tile[(quad*4 + rr)*260 + col] = f2bf(acc_c[fn][rr]);
  }
  __syncthreads();
  #pragma unroll
  for (int p = 0; p < 2; ++p) {
    const int g = t + p*256;
    const int oct = g >> 8, c = g & 255;
    ushort tmp[8];
    #pragma unroll
    for (int j = 0; j < 8; ++j) tmp[j] = tile[(oct*8 + j)*260 + c];
    const long og = ((r0 & 511) >> 3) + oct;     // node-octet within batch
    *(uint4*)(nfcpk + ((long)b*16384 + og*256 + c)*8) = *(uint4*)tmp;
  }
}

// ---------------------------------------------------------------------------
// K2: tiled edge scoring. Block = (b, 32-row i-tile, 128-col j-tile).
__global__ __launch_bounds__(256) void edge_kernel(
    const float* __restrict__ e1, const float* __restrict__ e2,
    const float* __restrict__ W2e, const float* __restrict__ b2e,
    const float* __restrict__ adjs, float* __restrict__ out_wadj,
    ushort* __restrict__ wadj_b, float* __restrict__ row_sum,
    float* __restrict__ l0_sum)
{
  const int b  = blockIdx.z;
  const int i0 = blockIdx.y * 32;
  const int j0 = blockIdx.x * 128;
  const int t  = threadIdx.x;

  __shared__ float e2s[32*132];

  #pragma unroll
  for (int itr = 0; itr < 4; ++itr) {
    const int idx = t + itr*256;
    const int kq = idx & 7, jg = idx >> 3;
    const float4 v = *(const float4*)(e2 + ((long)(b*Nn + j0 + jg))*Ee + kq*4);
    e2s[(kq*4+0)*132 + jg] = v.x;
    e2s[(kq*4+1)*132 + jg] = v.y;
    e2s[(kq*4+2)*132 + jg] = v.z;
    e2s[(kq*4+3)*132 + jg] = v.w;
  }

  const int pair  = t >> 4;
  const int jslot = t & 15;
  const int ia = i0 + pair*2;
  const int ib = ia + 1;
  const int ja = jslot*4;
  const int jb = ja + 64;

  float e1af[32], e1bf[32], w2f[32];
  #pragma unroll
  for (int q = 0; q < 8; ++q) {
    *(float4*)(&e1af[q*4]) = *(const float4*)(e1 + ((long)(b*Nn + ia))*Ee + q*4);
    *(float4*)(&e1bf[q*4]) = *(const float4*)(e1 + ((long)(b*Nn + ib))*Ee + q*4);
    *(float4*)(&w2f[q*4])  = *(const float4*)(W2e + q*4);
  }
  const float b2 = b2e[0];
  __syncthreads();

  float acc[2][8] = {};
  #pragma unroll
  for (int k = 0; k < 32; ++k) {
    const float4 va = *(const float4*)(e2s + k*132 + ja);
    const float4 vb = *(const float4*)(e2s + k*132 + jb);
    const float w = w2f[k];
    const float ea = e1af[k], eb = e1bf[k];
    acc[0][0] += fmaxf(ea+va.x, 0.f)*w;
    acc[0][1] += fmaxf(ea+va.y, 0.f)*w;
    acc[0][2] += fmaxf(ea+va.z, 0.f)*w;
    acc[0][3] += fmaxf(ea+va.w, 0.f)*w;
    acc[0][4] += fmaxf(ea+vb.x, 0.f)*w;
    acc[0][5] += fmaxf(ea+vb.y, 0.f)*w;
    acc[0][6] += fmaxf(ea+vb.z, 0.f)*w;
    acc[0][7] += fmaxf(ea+vb.w, 0.f)*w;
    acc[1][0] += fmaxf(eb+va.x, 0.f)*w;
    acc[1][1] += fmaxf(eb+va.y, 0.f)*w;
    acc[1][2] += fmaxf(eb+va.z, 0.f)*w;
    acc[1][3] += fmaxf(eb+va.w, 0.f)*w;
    acc[1][4] += fmaxf(eb+vb.x, 0.f)*w;
    acc[1][5] += fmaxf(eb+vb.y, 0.f)*w;
    acc[1][6] += fmaxf(eb+vb.z, 0.f)*w;
    acc[1][7] += fmaxf(eb+vb.w, 0.f)*w;
  }

  float rs[2] = {0.f, 0.f};
  float l0acc = 0.f;
  #pragma unroll
  for (int ii = 0; ii < 2; ++ii) {
    const int i = (ii == 0) ? ia : ib;
    const float* arow = adjs     + ((long)(b*Nn + i))*Nn + j0;
    ushort* bwrow     = wadj_b   + ((long)(b*Nn + i))*Nn + j0;
    float* outrow     = out_wadj + ((long)(b*Nn + i))*Nn + j0;
    #pragma unroll
    for (int h2 = 0; h2 < 2; ++h2) {
      const int jl = (h2 == 0) ? ja : jb;
      const float4 av = *(const float4*)(arow + jl);
      float wv[4];
      #pragma unroll
      for (int c = 0; c < 4; ++c) {
        const float logA = acc[ii][h2*4 + c] + b2;
        const float sg = 1.f/(1.f + expf(-logA));
        const float gate = fminf(fmaxf(sg*1.2f - 0.1f, 0.f), 1.f);
        const float a = (c==0)?av.x:(c==1)?av.y:(c==2)?av.z:av.w;
        const float w = gate*a*a;
        wv[c] = w;
        rs[ii] += w;
        l0acc += 1.f/(1.f + expf(-(logA + 1.58261088f)));
      }
      ushort4 bw;
      bw.x = f2bf(wv[0]); bw.y = f2bf(wv[1]); bw.z = f2bf(wv[2]); bw.w = f2bf(wv[3]);
      *(ushort4*)(bwrow + jl) = bw;
      outrow[jl+0] = wv[0]; outrow[jl+1] = wv[1];   // out+17: 4B-aligned only
      outrow[jl+2] = wv[2]; outrow[jl+3] = wv[3];
    }
  }

  #pragma unroll
  for (int m = 1; m < 16; m <<= 1) {
    rs[0] += __shfl_xor(rs[0], m, 16);
    rs[1] += __shfl_xor(rs[1], m, 16);
  }
  if (jslot == 0) {
    atomicAdd(&row_sum[b*Nn + ia], rs[0]);
    atomicAdd(&row_sum[b*Nn + ib], rs[1]);
  }
  #pragma unroll
  for (int m = 1; m < 64; m <<= 1) l0acc += __shfl_xor(l0acc, m, 64);
  if ((t & 63) == 0) atomicAdd(l0_sum, l0acc);
}

// ---------------------------------------------------------------------------
// K3: gemm_pool. h_tile = relu((wadj/rs)@nfc + bconv), attention-pool tile
// into gr. Double-buffered staging: one barrier per K-iter.
__global__ __launch_bounds__(256) void gemm_pool(
    const ushort* __restrict__ wadjb, const ushort* __restrict__ nfcpk,
    const float* __restrict__ row_sum, const float* __restrict__ masks,
    const float* __restrict__ bconv, float* __restrict__ gr)
{
  const int bb = blockIdx.z;
  const int m0 = blockIdx.y*64, n0 = blockIdx.x*64;
  const int t = threadIdx.x;
  const int lane = t & 63, l15 = lane & 15, quad = lane >> 4;
  const int wv = t >> 6, wr = wv & 1, wc = wv >> 1;

  __shared__ ushort As[2][259*8];            // granule (akq*65 + m)*8 (dbuf)
  __shared__ ushort Bs[2][256*8];            // granule (bkq*64 + n)*8 (dbuf)
  __shared__ float ptile[64*65];             // weighted h tile
  __shared__ float red[256];
  __shared__ float attn_s[64];
  __shared__ float mx_s, sinv_s;

  const ushort* Ab = wadjb + (long)bb*262144;
  const ushort* Bb = nfcpk + (long)bb*131072;
  const int am = t >> 2, akq = t & 3;
  const int bn = t & 63, bkq = t >> 6;

  f32x4 acc[2][2];
  #pragma unroll
  for (int i = 0; i < 2; ++i)
    #pragma unroll
    for (int j = 0; j < 2; ++j) acc[i][j] = (f32x4){0.f,0.f,0.f,0.f};

  // stage k=0 into buf0, prefetch k=32
  uint4 ra = *(const uint4*)(Ab + (long)(m0+am)*512 + akq*8);
  uint4 rb = *(const uint4*)(Bb + ((long)bkq*256 + n0 + bn)*8);
  *(uint4*)(As[0] + (akq*65 + am)*8) = ra;
  *(uint4*)(Bs[0] + (bkq*64 + bn)*8) = rb;
  ra = *(const uint4*)(Ab + (long)(m0+am)*512 + 32 + akq*8);
  rb = *(const uint4*)(Bb + ((long)(4 + bkq)*256 + n0 + bn)*8);

  for (int k0 = 0; k0 < 512; k0 += 32) {
    const int pb = (k0 >> 5) & 1;
    __syncthreads();
    if (k0 + 32 < 512) {
      *(uint4*)(As[1-pb] + (akq*65 + am)*8) = ra;
      *(uint4*)(Bs[1-pb] + (bkq*64 + bn)*8) = rb;
      if (k0 + 64 < 512) {
        ra = *(const uint4*)(Ab + (long)(m0+am)*512 + (k0+64) + akq*8);
        rb = *(const uint4*)(Bb + ((long)(((k0+64) >> 3) + bkq)*256 + n0 + bn)*8);
      }
    }
    bf16x8 af[2], bfr[2];
    #pragma unroll
    for (int i = 0; i < 2; ++i)
      af[i] = *(const bf16x8*)(As[pb] + (quad*65 + wr*32 + i*16 + l15)*8);
    #pragma unroll
    for (int j = 0; j < 2; ++j)
      bfr[j] = *(const bf16x8*)(Bs[pb] + (quad*64 + wc*32 + j*16 + l15)*8);
    #pragma unroll
    for (int i = 0; i < 2; ++i)
      #pragma unroll
      for (int j = 0; j < 2; ++j)
        acc[i][j] = __builtin_amdgcn_mfma_f32_16x16x32_bf16(
            af[i], bfr[j], acc[i][j], 0, 0, 0);
  }
  __syncthreads();

  // attention softmax over this batch's masked degrees (block-redundant)
  {
    const float mk0 = masks[bb*Nn + t], mk1 = masks[bb*Nn + t + 256];
    const float lv0 = (mk0 > 0.f) ? row_sum[bb*Nn + t] : -1e9f;
    const float lv1 = (mk1 > 0.f) ? row_sum[bb*Nn + t + 256] : -1e9f;
    red[t] = fmaxf(lv0, lv1); __syncthreads();
    for (int s = 128; s > 0; s >>= 1) { if (t < s) red[t] = fmaxf(red[t], red[t+s]); __syncthreads(); }
    if (t == 0) mx_s = red[0];
    __syncthreads();
    const float mx = mx_s;
    red[t] = expf(lv0 - mx) + expf(lv1 - mx); __syncthreads();
    for (int s = 128; s > 0; s >>= 1) { if (t < s) red[t] += red[t+s]; __syncthreads(); }
    if (t == 0) sinv_s = 1.f/red[0];
    __syncthreads();
    if (t < 64) {
      const int node = m0 + t;
      const float mm = masks[bb*Nn + node];
      const float lv = (mm > 0.f) ? row_sum[bb*Nn + node] : -1e9f;
      attn_s[t] = expf(lv - mx)*sinv_s;
    }
    __syncthreads();
  }

  // epilogue: h = relu(acc/rs + bias), weight by attn, stash in LDS
  #pragma unroll
  for (int i = 0; i < 2; ++i) {
    #pragma unroll
    for (int j = 0; j < 2; ++j) {
      const int lcol = wc*32 + j*16 + l15;
      const float bias = bconv[n0 + lcol];
      #pragma unroll
      for (int rr = 0; rr < 4; ++rr) {
        const int lrow = wr*32 + i*16 + quad*4 + rr;
        const int row = m0 + lrow;
        const float scl = 1.f/(row_sum[bb*Nn + row] + 1e-8f);
        const float hv = fmaxf(acc[i][j][rr]*scl + bias, 0.f);
        ptile[lrow*65 + lcol] = hv * attn_s[lrow];
      }
    }
  }
  __syncthreads();
  if (t < 64) {
    float s = 0.f;
    #pragma unroll 4
    for (int rr = 0; rr < 64; ++rr) s += ptile[rr*65 + t];
    atomicAdd(&gr[bb*Hh + n0 + t], s);
  }
}

// ---------------------------------------------------------------------------
// K4: classifier head + spectral norm + losses. Single block.
__global__ __launch_bounds__(256) void classifier_kernel(
    const float* __restrict__ gr, const float* __restrict__ W1c,
    const float* __restrict__ b1c, const float* __restrict__ ln_g,
    const float* __restrict__ ln_b, const float* __restrict__ W2c,
    const float* __restrict__ b2c, const float* __restrict__ u_sn,
    const int* __restrict__ labels, const float* __restrict__ l0_sum,
    float* __restrict__ out)
{
  const int t = threadIdx.x;
  __shared__ float grs[2048];
  __shared__ float z[8][128];
  __shared__ float red[256];
  __shared__ float vv[128];
  __shared__ float mu_s[8], ri_s[8];
  __shared__ float lg[16];
  for (int p = t; p < 2048; p += 256) grs[p] = gr[p];
  __syncthreads();
  #pragma unroll
  for (int p = 0; p < 4; ++p) {
    const int idx = t + p*256;
    const int b = idx >> 7, o = idx & 127;
    float acc = b1c[o];
    for (int d = 0; d < 256; ++d) acc += grs[b*256 + d]*W1c[d*128 + o];
    z[b][o] = fmaxf(acc, 0.f);
  }
  __syncthreads();
  if (t < 8) {
    float mu = 0.f;
    for (int o = 0; o < 128; ++o) mu += z[t][o];
    mu *= (1.f/128.f);
    float var = 0.f;
    for (int o = 0; o < 128; ++o) { const float d = z[t][o]-mu; var += d*d; }
    var *= (1.f/128.f);
    mu_s[t] = mu; ri_s[t] = rsqrtf(var + 1e-5f);
  }
  const float u0 = u_sn[0], u1 = u_sn[1];
  float vt = 0.f;
  if (t < 128) { vt = W2c[2*t]*u0 + W2c[2*t+1]*u1; vv[t] = vt; }
  red[t] = (t < 128) ? vt*vt : 0.f;
  __syncthreads();
  for (int s = 128; s > 0; s >>= 1) { if (t < s) red[t] += red[t+s]; __syncthreads(); }
  const float vninv = 1.f/fmaxf(sqrtf(red[0]), 1e-12f);
  __syncthreads();
  red[t] = (t < 128) ? W2c[2*t]*vv[t]*vninv : 0.f;
  __syncthreads();
  for (int s = 128; s > 0; s >>= 1) { if (t < s) red[t] += red[t+s]; __syncthreads(); }
  const float u20 = red[0];
  __syncthreads();
  red[t] = (t < 128) ? W2c[2*t+1]*vv[t]*vninv : 0.f;
  __syncthreads();
  for (int s = 128; s > 0; s >>= 1) { if (t < s) red[t] += red[t+s]; __syncthreads(); }
  const float u21 = red[0];
  __syncthreads();
  const float uninv = 1.f/fmaxf(sqrtf(u20*u20 + u21*u21), 1e-12f);
  const float u2n0 = u20*uninv, u2n1 = u21*uninv;
  red[t] = (t < 128) ? vv[t]*vninv*(W2c[2*t]*u2n0 + W2c[2*t+1]*u2n1) : 0.f;
  __syncthreads();
  for (int s = 128; s > 0; s >>= 1) { if (t < s) red[t] += red[t+s]; __syncthreads(); }
  const float sinv = 1.f/red[0];
  __syncthreads();
  if (t < 16) {
    const int b = t >> 1, c = t & 1;
    const float mu = mu_s[b], ri = ri_s[b];
    float acc = 0.f;
    for (int o = 0; o < 128; ++o) {
      const float zln = (z[b][o]-mu)*ri*ln_g[o] + ln_b[o];
      acc += zln*W2c[2*o + c];
    }
    const float lgv = acc*sinv + b2c[c];
    lg[t] = lgv;
    out[t] = lgv;
  }
  __syncthreads();
  if (t == 0) {
    float closs = 0.f;
    for (int b = 0; b < 8; ++b) {
      const float a0 = lg[2*b], a1 = lg[2*b+1];
      const float m = fmaxf(a0, a1);
      const float lse = m + logf(expf(a0-m) + expf(a1-m));
      closs += lse - lg[2*b + labels[b]];
    }
    closs *= (1.f/8.f);
    out[16] = closs + 0.01f*l0_sum[0];
  }
}

extern "C" void kernel_launch(void* const* d_in, const int* in_sizes, int n_in,
                              void* d_out, int out_size, void* d_ws, size_t ws_size,
                              hipStream_t stream) {
  const float* node_feat = (const float*)d_in[0];
  const int*   labels    = (const int*)d_in[1];
  const float* adjs      = (const float*)d_in[2];
  const float* masks     = (const float*)d_in[3];
  const float* Wa        = (const float*)d_in[4];
  const float* Wb        = (const float*)d_in[5];
  const float* be        = (const float*)d_in[6];
  const float* W2e       = (const float*)d_in[7];
  const float* b2e       = (const float*)d_in[8];
  const float* Wconv     = (const float*)d_in[9];
  const float* bconv     = (const float*)d_in[10];
  const float* W1c       = (const float*)d_in[11];
  const float* b1c       = (const float*)d_in[12];
  const float* ln_g      = (const float*)d_in[13];
  const float* ln_b      = (const float*)d_in[14];
  const float* W2c       = (const float*)d_in[15];
  const float* b2c       = (const float*)d_in[16];
  const float* u_sn      = (const float*)d_in[17];

  float* out = (float*)d_out;
  float* ws  = (float*)d_ws;
  ushort* nfcpk  = (ushort*)(ws + WS_NFCPK);
  float*  e1     = ws + WS_E1;
  float*  e2     = ws + WS_E2;
  ushort* wadjb  = (ushort*)(ws + WS_WADJB);
  float*  row_sum= ws + WS_RS;
  float*  l0s    = ws + WS_L0;
  float*  gr     = ws + WS_GR;
  ushort* wabpk  = (ushort*)(ws + WS_WABPK);
  ushort* wcpk   = (ushort*)(ws + WS_WCPK);

  pack_weights<<<80, 256, 0, stream>>>(Wconv, Wa, Wb, wcpk, wabpk);
  norm_e12_nfc<<<256, 256, 0, stream>>>(node_feat, wabpk, wcpk, be, nfcpk,
                                        e1, e2, row_sum, gr, l0s);
  edge_kernel<<<dim3(Nn/128, Nn/32, Bsz), 256, 0, stream>>>(
      e1, e2, W2e, b2e, adjs, out + 17, wadjb, row_sum, l0s);
  gemm_pool<<<dim3(Hh/64, Nn/64, Bsz), 256, 0, stream>>>(
      wadjb, nfcpk, row_sum, masks, bconv, gr);
  classifier_kernel<<<1, 256, 0, stream>>>(gr, W1c, b1c, ln_g, ln_b, W2c, b2c,
                                           u_sn, labels, l0s, out);
}